// Round 7
// baseline (3853.664 us; speedup 1.0000x reference)
//
#include <hip/hip_runtime.h>
#include <hip/hip_cooperative_groups.h>
#include <math.h>

namespace cg = cooperative_groups;

#define DC 8220      // dist row stride (28 + 8192)
#define OFF 28
#define NR 4096      // rows of M
#define NC 8192      // cols of M
#define INV4096 (1.0f / 4096.0f)
#define INV8192 (1.0f / 8192.0f)
#define BLK 256

#define AGENT __HIP_MEMORY_SCOPE_AGENT

__device__ __forceinline__ float bflo(unsigned int u) { return __uint_as_float(u << 16); }
__device__ __forceinline__ float bfhi(unsigned int u) { return __uint_as_float(u & 0xffff0000u); }
__device__ __forceinline__ unsigned short f2bf(float f) {
    unsigned int i = __float_as_uint(f);
    return (unsigned short)((i + 0x7fffu + ((i >> 16) & 1u)) >> 16);   // RNE
}
// bf16 coherent weight store/load (2B atomics at agent scope)
__device__ __forceinline__ void st_wbf(unsigned short* p, float v) {
    __hip_atomic_store(p, f2bf(v), __ATOMIC_RELAXED, AGENT);
}
__device__ __forceinline__ float ld_wbf(const unsigned short* p) {
    unsigned short u = __hip_atomic_load(p, __ATOMIC_RELAXED, AGENT);
    return __uint_as_float(((unsigned int)u) << 16);
}

// --------------- tree grid barrier (no cache flush, spread counters) -------
__device__ __forceinline__ void gbar(unsigned int* ctrs, unsigned int* rel,
                                     unsigned int phase, int bid, int cpl) {
    __syncthreads();
    if (threadIdx.x == 0) {
        asm volatile("s_waitcnt vmcnt(0)" ::: "memory");   // drain prior stores
        __hip_atomic_fetch_add(&ctrs[(bid & 63) * 16], 1u, __ATOMIC_RELAXED, AGENT);
    }
    if (bid == 0) {
        if (threadIdx.x < 64) {
            unsigned int tgt = phase * (unsigned int)cpl;
            while (__hip_atomic_load(&ctrs[threadIdx.x * 16], __ATOMIC_RELAXED, AGENT) < tgt)
                __builtin_amdgcn_s_sleep(2);
        }
        __syncthreads();
        if (threadIdx.x == 0)
            __hip_atomic_store(rel, phase, __ATOMIC_RELAXED, AGENT);
    }
    if (threadIdx.x == 0) {
        while (__hip_atomic_load(rel, __ATOMIC_RELAXED, AGENT) < phase)
            __builtin_amdgcn_s_sleep(2);
    }
    __syncthreads();
}

// stage n bf16 weights (coherent) into LDS (contiguous copy, 8B granules)
__device__ __forceinline__ void stage_hbf(const unsigned short* __restrict__ wbf,
                                          unsigned long long* lds64, int nelem, int tid) {
    for (int g = tid; g < (nelem >> 2); g += BLK)
        lds64[g] = __hip_atomic_load((const unsigned long long*)wbf + g,
                                     __ATOMIC_RELAXED, AGENT);
    __syncthreads();
}

// 4096-wide bf16 dot: M row chunk x bf16 weights in LDS; lane0 holds result
__device__ __forceinline__ float dot4096(const unsigned short* __restrict__ mrow,
                                         const unsigned int* vv32, int lane) {
    float acc = 0.0f;
#pragma unroll
    for (int k = 0; k < 8; ++k) {
        int j = k * 512 + lane * 8;
        uint4 a = *(const uint4*)(mrow + j);
        uint4 w = *(const uint4*)(vv32 + (j >> 1));
        acc = fmaf(bflo(a.x), bflo(w.x), acc);
        acc = fmaf(bfhi(a.x), bfhi(w.x), acc);
        acc = fmaf(bflo(a.y), bflo(w.y), acc);
        acc = fmaf(bfhi(a.y), bfhi(w.y), acc);
        acc = fmaf(bflo(a.z), bflo(w.z), acc);
        acc = fmaf(bfhi(a.z), bfhi(w.z), acc);
        acc = fmaf(bflo(a.w), bflo(w.w), acc);
        acc = fmaf(bfhi(a.w), bfhi(w.w), acc);
    }
#pragma unroll
    for (int o = 32; o; o >>= 1) acc += __shfl_down(acc, o);
    return acc;
}

// ---------------- shared builders (main + fallback) ------------------------
__device__ __forceinline__ void build1_chunk(const float* __restrict__ dist,
                                             const float* __restrict__ rm1,
                                             unsigned short* __restrict__ M, int c) {
    int i = c >> 10;
    int j = (c & 1023) << 3;
    float rm = rm1[i];
    const float* Dr = dist + (size_t)i * DC + OFF + j;
    float4 d0 = *(const float4*)Dr;
    float4 d1 = *(const float4*)(Dr + 4);
    float dv[8] = {d0.x, d0.y, d0.z, d0.w, d1.x, d1.y, d1.z, d1.w};
    unsigned short e[8];
#pragma unroll
    for (int k = 0; k < 8; ++k) {
        int jj = j + k;
        bool diag = (jj == i) || (jj == i + 4096);
        float gm = diag ? 0.0f : fmaxf(0.05f + dv[k] - rm, 0.0f);
        e[k] = f2bf(__expf(5.0f * __expf(-gm)));
    }
    uint4 o;
    o.x = (unsigned int)e[0] | ((unsigned int)e[1] << 16);
    o.y = (unsigned int)e[2] | ((unsigned int)e[3] << 16);
    o.z = (unsigned int)e[4] | ((unsigned int)e[5] << 16);
    o.w = (unsigned int)e[6] | ((unsigned int)e[7] << 16);
    *(uint4*)(M + (size_t)c * 8) = o;
}

__device__ __forceinline__ void build2_chunk(const float* __restrict__ dist,
                                             const float* __restrict__ d12,
                                             unsigned short* __restrict__ M, int c) {
    int r = c >> 10;
    int col = (c & 1023) << 3;
    const float* Dr = dist + (size_t)r * DC + OFF + col;
    float4 d0 = *(const float4*)Dr;
    float4 d1 = *(const float4*)(Dr + 4);
    float4 e0 = *(const float4*)(d12 + col);
    float4 e1 = *(const float4*)(d12 + col + 4);
    float dv[8] = {d0.x, d0.y, d0.z, d0.w, d1.x, d1.y, d1.z, d1.w};
    float dd[8] = {e0.x, e0.y, e0.z, e0.w, e1.x, e1.y, e1.z, e1.w};
    unsigned short e[8];
#pragma unroll
    for (int k = 0; k < 8; ++k) {
        int cc = col + k;
        bool diag = (r == (cc & 4095));
        float gm = diag ? 0.0f : fmaxf(0.05f + dv[k] - dd[k], 0.0f);
        e[k] = f2bf(__expf(5.0f * __expf(-gm)));
    }
    uint4 o;
    o.x = (unsigned int)e[0] | ((unsigned int)e[1] << 16);
    o.y = (unsigned int)e[2] | ((unsigned int)e[3] << 16);
    o.z = (unsigned int)e[4] | ((unsigned int)e[5] << 16);
    o.w = (unsigned int)e[6] | ((unsigned int)e[7] << 16);
    *(uint4*)(M + (size_t)c * 8) = o;
}

__device__ __forceinline__ void tile_transpose(const unsigned short* __restrict__ M,
                                               unsigned short* __restrict__ MT,
                                               unsigned int (*tile)[33], int t, int tid) {
    int r0 = (t >> 7) * 64;
    int c0 = (t & 127) * 64;
    int lc = tid & 7, rr = tid >> 3;
#pragma unroll
    for (int s = 0; s < 2; ++s) {
        int r = rr + s * 32;
        uint4 a = *(const uint4*)(M + (size_t)(r0 + r) * NC + c0 + lc * 8);
        tile[r][lc * 4 + 0] = a.x;
        tile[r][lc * 4 + 1] = a.y;
        tile[r][lc * 4 + 2] = a.z;
        tile[r][lc * 4 + 3] = a.w;
    }
    __syncthreads();
    int cc = tid >> 2, rs = (tid & 3) * 16;
    unsigned int o[8];
#pragma unroll
    for (int w = 0; w < 8; ++w) {
        unsigned int ue = tile[rs + 2 * w][cc >> 1];
        unsigned int uo = tile[rs + 2 * w + 1][cc >> 1];
        unsigned short e = (cc & 1) ? (unsigned short)(ue >> 16) : (unsigned short)(ue & 0xffffu);
        unsigned short d = (cc & 1) ? (unsigned short)(uo >> 16) : (unsigned short)(uo & 0xffffu);
        o[w] = (unsigned int)e | ((unsigned int)d << 16);
    }
    unsigned short* dst = MT + (size_t)(c0 + cc) * NR + r0 + rs;
    *(uint4*)dst = make_uint4(o[0], o[1], o[2], o[3]);
    *(uint4*)(dst + 8) = make_uint4(o[4], o[5], o[6], o[7]);
    __syncthreads();
}

// ------------------------- cooperative persistent kernel -------------------
__global__ __launch_bounds__(BLK, 8) void k_main(const float* __restrict__ dist,
                                                 float* __restrict__ out,
                                                 unsigned short* __restrict__ M,
                                                 unsigned short* __restrict__ MT,
                                                 unsigned short* __restrict__ wrowH,
                                                 unsigned short* __restrict__ wcolH,
                                                 float* __restrict__ rm1,
                                                 int* __restrict__ arg1,
                                                 float* __restrict__ d12,
                                                 float* __restrict__ numb,
                                                 float* __restrict__ denb,
                                                 unsigned int* __restrict__ ctrs,
                                                 unsigned int* __restrict__ rel) {
    cg::grid_group grid = cg::this_grid();
    const int tid = threadIdx.x, bid = blockIdx.x;
    const int nb = gridDim.x, nt = nb * BLK;
    const int gt = bid * BLK + tid;
    const int nw = nt >> 6, wave = gt >> 6, lane = tid & 63, wl = tid >> 6;
    const int cpl = nb >> 6;
    unsigned int pc = 0;

    extern __shared__ char smem[];                       // 16512 B dynamic
    unsigned long long* vvl64 = (unsigned long long*)smem;   // 16 KB weights
    unsigned int* vv32 = (unsigned int*)smem;
    unsigned int (*tile)[33] = (unsigned int(*)[33])smem;    // 8.4 KB (reuse)
    float* wsm = (float*)smem;                               // epi2 (reuse)
    float* pd = (float*)(smem + 16384);                      // 8 floats combine

    // ---------------- init ----------------
    for (int t = gt; t < NC; t += nt) {
        if (t == 0) __hip_atomic_store(out, 0.0f, __ATOMIC_RELAXED, AGENT);
        if (t < NR) {
            float a = dist[(size_t)t * DC + OFF + t];
            float b = dist[(size_t)t * DC + OFF + 4096 + t];
            rm1[t] = fmaxf(a, b);
            arg1[t] = (a >= b) ? t : t + 4096;
            st_wbf(&wrowH[t], INV4096);                  // u0 (exact in bf16)
        }
        d12[t] = dist[(size_t)(t & 4095) * DC + OFF + t];
    }
    grid.sync();
    for (int c = gt; c < NR * NC / 8; c += nt) build1_chunk(dist, rm1, M, c);
    grid.sync();
    for (int t = bid; t < 8192; t += nb) tile_transpose(M, MT, tile, t, tid);
    grid.sync();

    // ---------------- loss1 Sinkhorn ----------------
    for (int it = 0; it < 50; ++it) {
        // A: wcol[r] = INV8192 / (MT[r] . wrow)
        stage_hbf(wrowH, vvl64, NR, tid);
        for (int r = wave; r < NC; r += nw) {
            float s = dot4096(MT + (size_t)r * NR, vv32, lane);
            if (lane == 0) st_wbf(&wcolH[r], __fdividef(INV8192, s));
        }
        gbar(ctrs, rel, ++pc, bid, cpl);
        if (it == 49) break;
        // B: wrow[i] = INV4096 / (M[i] . wcol)  -- 2 waves per row
        stage_hbf(wcolH, vvl64, NC, tid);
        for (int u = wave; u < 2 * NR; u += nw) {
            int row = u >> 1, half = u & 1;
            float s = dot4096(M + (size_t)row * NC + half * 4096,
                              vv32 + half * 2048, lane);
            if (lane == 0) pd[wl] = s;
            __syncthreads();
            if ((wl & 1) == 0 && lane == 0)
                st_wbf(&wrowH[row], __fdividef(INV4096, pd[wl] + pd[wl + 1]));
            __syncthreads();
        }
        gbar(ctrs, rel, ++pc, bid, cpl);
    }

    // ---------------- epi1: 2 waves per row ----------------
    stage_hbf(wcolH, vvl64, NC, tid);
    for (int u = wave; u < 2 * NR; u += nw) {
        int i = u >> 1, half = u & 1;
        float rm = rm1[i];
        int arg = arg1[i];
        const unsigned short* Ar = M + (size_t)i * NC + half * 4096;
        const float* Dr = dist + (size_t)i * DC + OFF + half * 4096;
        const unsigned int* vs = vv32 + half * 2048;
        float num = 0.0f, den = 0.0f;
#pragma unroll 4
        for (int k = 0; k < 8; ++k) {
            int j0 = k * 512 + lane * 8;
            uint4 a = *(const uint4*)(Ar + j0);
            uint4 w = *(const uint4*)(vs + (j0 >> 1));
            float4 d0 = *(const float4*)(Dr + j0);
            float4 d1 = *(const float4*)(Dr + j0 + 4);
            float av[8] = {bflo(a.x), bfhi(a.x), bflo(a.y), bfhi(a.y),
                           bflo(a.z), bfhi(a.z), bflo(a.w), bfhi(a.w)};
            float tv[8] = {bflo(w.x), bfhi(w.x), bflo(w.y), bfhi(w.y),
                           bflo(w.z), bfhi(w.z), bflo(w.w), bfhi(w.w)};
            float dv[8] = {d0.x, d0.y, d0.z, d0.w, d1.x, d1.y, d1.z, d1.w};
#pragma unroll
            for (int e = 0; e < 8; ++e) {
                int jj = half * 4096 + j0 + e;
                bool isdiag = (jj == i) || (jj == i + 4096);
                float gm = isdiag ? fmaxf(rm - 0.5f - dv[e], 0.0f)
                                  : fmaxf(0.05f + dv[e] - rm, 0.0f);
                bool keep = (jj != arg) && ((jj < 4096) || (jj == i + 4096));
                float wv = keep ? av[e] * tv[e] : 0.0f;
                num += wv * gm;
                den += wv;
            }
        }
#pragma unroll
        for (int o = 32; o; o >>= 1) {
            num += __shfl_down(num, o);
            den += __shfl_down(den, o);
        }
        if (lane == 0) { pd[wl] = num; pd[4 + wl] = den; }
        __syncthreads();
        if ((wl & 1) == 0 && lane == 0)
            atomicAdd(out, (pd[wl] + pd[wl + 1]) / (pd[4 + wl] + pd[4 + wl + 1]));
        __syncthreads();
    }
    gbar(ctrs, rel, ++pc, bid, cpl);          // all M readers done before overwrite

    // ---------------- build M2 (= K2^T) + loss2 init ----------------
    for (int t = gt; t < NC; t += nt) {
        st_wbf(&wcolH[t], INV8192);                      // u2_0 (exact)
        __hip_atomic_store(&numb[t], 0.0f, __ATOMIC_RELAXED, AGENT);
        __hip_atomic_store(&denb[t], 0.0f, __ATOMIC_RELAXED, AGENT);
    }
    for (int c = gt; c < NR * NC / 8; c += nt) build2_chunk(dist, d12, M, c);
    grid.sync();
    for (int t = bid; t < 8192; t += nb) tile_transpose(M, MT, tile, t, tid);
    grid.sync();

    // ---------------- loss2 Sinkhorn ----------------
    for (int it = 0; it < 50; ++it) {
        // B2: wrow[row] = INV4096 / (M[row] . wcol)   (v2 update)
        stage_hbf(wcolH, vvl64, NC, tid);
        for (int u = wave; u < 2 * NR; u += nw) {
            int row = u >> 1, half = u & 1;
            float s = dot4096(M + (size_t)row * NC + half * 4096,
                              vv32 + half * 2048, lane);
            if (lane == 0) pd[wl] = s;
            __syncthreads();
            if ((wl & 1) == 0 && lane == 0)
                st_wbf(&wrowH[row], __fdividef(INV4096, pd[wl] + pd[wl + 1]));
            __syncthreads();
        }
        gbar(ctrs, rel, ++pc, bid, cpl);
        if (it == 49) break;
        // A2: wcol[r] = INV8192 / (MT[r] . wrow)  (u2 update)
        stage_hbf(wrowH, vvl64, NR, tid);
        for (int r = wave; r < NC; r += nw) {
            float s = dot4096(MT + (size_t)r * NR, vv32, lane);
            if (lane == 0) st_wbf(&wcolH[r], __fdividef(INV8192, s));
        }
        gbar(ctrs, rel, ++pc, bid, cpl);
    }

    // ---------------- epi2: column stripes over M2 ----------------
    for (int t = bid; t < 512; t += nb) {
        int r0 = (t >> 3) * 64;
        int c = (t & 7) * 1024 + tid * 4;
        if (tid < 64) wsm[tid] = ld_wbf(&wrowH[r0 + tid]);
        __syncthreads();
        float4 e0 = *(const float4*)(d12 + c);
        float dd[4] = {e0.x, e0.y, e0.z, e0.w};
        float nacc[4] = {0.f, 0.f, 0.f, 0.f};
        float dacc[4] = {0.f, 0.f, 0.f, 0.f};
        for (int r = 0; r < 64; ++r) {
            int rr = r0 + r;
            uint2 a = *(const uint2*)(M + (size_t)rr * NC + c);
            float4 dv4 = *(const float4*)(dist + (size_t)rr * DC + OFF + c);
            float av[4] = {bflo(a.x), bfhi(a.x), bflo(a.y), bfhi(a.y)};
            float dv[4] = {dv4.x, dv4.y, dv4.z, dv4.w};
            float ww = wsm[r];
#pragma unroll
            for (int e = 0; e < 4; ++e) {
                int cc = c + e;
                bool isdiag = (rr == (cc & 4095));
                float gm = fmaxf(0.05f + dv[e] - dd[e], 0.0f);
                float wv = isdiag ? 0.0f : av[e] * ww;
                nacc[e] += wv * gm;
                dacc[e] += wv;
            }
        }
#pragma unroll
        for (int e = 0; e < 4; ++e) {
            atomicAdd(&numb[c + e], nacc[e]);
            atomicAdd(&denb[c + e], dacc[e]);
        }
        __syncthreads();
    }
    gbar(ctrs, rel, ++pc, bid, cpl);
    for (int t = wave; t < 128; t += nw) {
        int c = t * 64 + lane;
        float n = __hip_atomic_load(&numb[c], __ATOMIC_RELAXED, AGENT);
        float d = __hip_atomic_load(&denb[c], __ATOMIC_RELAXED, AGENT);
        float v = n / d;
#pragma unroll
        for (int o = 32; o; o >>= 1) v += __shfl_down(v, o);
        if (lane == 0) atomicAdd(out, v);
    }
}

// ------------------------- fallback multi-kernel path (f32 weights) --------
template <int W>
__device__ __forceinline__ float rowdot_g(const unsigned short* __restrict__ row,
                                          const float* __restrict__ w, int lane) {
    float acc = 0.0f;
#pragma unroll
    for (int s = 0; s < W; s += 512) {
        int j = s + lane * 8;
        uint4 a = *(const uint4*)(row + j);
        float4 w0 = *(const float4*)(w + j);
        float4 w1 = *(const float4*)(w + j + 4);
        acc = fmaf(bflo(a.x), w0.x, acc);
        acc = fmaf(bfhi(a.x), w0.y, acc);
        acc = fmaf(bflo(a.y), w0.z, acc);
        acc = fmaf(bfhi(a.y), w0.w, acc);
        acc = fmaf(bflo(a.z), w1.x, acc);
        acc = fmaf(bfhi(a.z), w1.y, acc);
        acc = fmaf(bflo(a.w), w1.z, acc);
        acc = fmaf(bfhi(a.w), w1.w, acc);
    }
#pragma unroll
    for (int o = 32; o; o >>= 1) acc += __shfl_down(acc, o);
    return acc;
}
__global__ __launch_bounds__(BLK) void k_fb_init(const float* __restrict__ dist,
                                                 float* __restrict__ rm1, int* __restrict__ arg1,
                                                 float* __restrict__ d12, float* __restrict__ wrow,
                                                 float* __restrict__ out) {
    int t = blockIdx.x * BLK + threadIdx.x;
    if (t == 0) out[0] = 0.0f;
    if (t < NR) {
        float a = dist[(size_t)t * DC + OFF + t];
        float b = dist[(size_t)t * DC + OFF + 4096 + t];
        rm1[t] = fmaxf(a, b);
        arg1[t] = (a >= b) ? t : t + 4096;
        wrow[t] = INV4096;
    }
    d12[t] = dist[(size_t)(t & 4095) * DC + OFF + t];
}
__global__ __launch_bounds__(BLK) void k_fb_build1(const float* __restrict__ dist,
                                                   const float* __restrict__ rm1,
                                                   unsigned short* __restrict__ M) {
    build1_chunk(dist, rm1, M, blockIdx.x * BLK + threadIdx.x);
}
__global__ __launch_bounds__(BLK) void k_fb_build2(const float* __restrict__ dist,
                                                   const float* __restrict__ d12,
                                                   unsigned short* __restrict__ M) {
    build2_chunk(dist, d12, M, blockIdx.x * BLK + threadIdx.x);
}
__global__ __launch_bounds__(BLK) void k_fb_transp(const unsigned short* __restrict__ M,
                                                   unsigned short* __restrict__ MT) {
    __shared__ unsigned int tile[64][33];
    tile_transpose(M, MT, tile, blockIdx.x, threadIdx.x);
}
template <int W>
__global__ __launch_bounds__(BLK) void k_fb_matvec(const unsigned short* __restrict__ Mat,
                                                   const float* __restrict__ w,
                                                   float* __restrict__ outv, float scale) {
    int r = blockIdx.x * 4 + (threadIdx.x >> 6);
    float s = rowdot_g<W>(Mat + (size_t)r * W, w, threadIdx.x & 63);
    if ((threadIdx.x & 63) == 0) outv[r] = __fdividef(scale, s);
}
__global__ __launch_bounds__(BLK) void k_fb_epi1(const unsigned short* __restrict__ M,
                                                 const float* __restrict__ dist,
                                                 const float* __restrict__ wcol,
                                                 const float* __restrict__ rm1,
                                                 const int* __restrict__ arg1,
                                                 float* __restrict__ out) {
    int i = blockIdx.x * 4 + (threadIdx.x >> 6);
    int lane = threadIdx.x & 63;
    float rm = rm1[i];
    int arg = arg1[i];
    const unsigned short* Ar = M + (size_t)i * NC;
    const float* Dr = dist + (size_t)i * DC + OFF;
    float num = 0.0f, den = 0.0f;
#pragma unroll 4
    for (int s = 0; s < NC; s += 512) {
        int j0 = s + lane * 8;
        uint4 a = *(const uint4*)(Ar + j0);
        float4 t0 = *(const float4*)(wcol + j0);
        float4 t1 = *(const float4*)(wcol + j0 + 4);
        float4 d0 = *(const float4*)(Dr + j0);
        float4 d1 = *(const float4*)(Dr + j0 + 4);
        float av[8] = {bflo(a.x), bfhi(a.x), bflo(a.y), bfhi(a.y),
                       bflo(a.z), bfhi(a.z), bflo(a.w), bfhi(a.w)};
        float tv[8] = {t0.x, t0.y, t0.z, t0.w, t1.x, t1.y, t1.z, t1.w};
        float dv[8] = {d0.x, d0.y, d0.z, d0.w, d1.x, d1.y, d1.z, d1.w};
#pragma unroll
        for (int e = 0; e < 8; ++e) {
            int jj = j0 + e;
            bool isdiag = (jj == i) || (jj == i + 4096);
            float gm = isdiag ? fmaxf(rm - 0.5f - dv[e], 0.0f)
                              : fmaxf(0.05f + dv[e] - rm, 0.0f);
            bool keep = (jj != arg) && ((jj < 4096) || (jj == i + 4096));
            float wv = keep ? av[e] * tv[e] : 0.0f;
            num += wv * gm;
            den += wv;
        }
    }
#pragma unroll
    for (int o = 32; o; o >>= 1) {
        num += __shfl_down(num, o);
        den += __shfl_down(den, o);
    }
    if (lane == 0) atomicAdd(out, num / den);
}
__global__ __launch_bounds__(BLK) void k_fb_init2(float* __restrict__ wcol,
                                                  float* __restrict__ numb,
                                                  float* __restrict__ denb) {
    int t = blockIdx.x * BLK + threadIdx.x;
    wcol[t] = INV8192;
    numb[t] = 0.0f;
    denb[t] = 0.0f;
}
__global__ __launch_bounds__(BLK) void k_fb_epi2(const unsigned short* __restrict__ M,
                                                 const float* __restrict__ dist,
                                                 const float* __restrict__ wrow,
                                                 const float* __restrict__ d12,
                                                 float* __restrict__ numb,
                                                 float* __restrict__ denb) {
    __shared__ float wsm[64];
    int t = blockIdx.x, tid = threadIdx.x;
    int r0 = (t >> 3) * 64;
    int c = (t & 7) * 1024 + tid * 4;
    if (tid < 64) wsm[tid] = wrow[r0 + tid];
    __syncthreads();
    float4 e0 = *(const float4*)(d12 + c);
    float dd[4] = {e0.x, e0.y, e0.z, e0.w};
    float nacc[4] = {0.f, 0.f, 0.f, 0.f};
    float dacc[4] = {0.f, 0.f, 0.f, 0.f};
    for (int r = 0; r < 64; ++r) {
        int rr = r0 + r;
        uint2 a = *(const uint2*)(M + (size_t)rr * NC + c);
        float4 dv4 = *(const float4*)(dist + (size_t)rr * DC + OFF + c);
        float av[4] = {bflo(a.x), bfhi(a.x), bflo(a.y), bfhi(a.y)};
        float dv[4] = {dv4.x, dv4.y, dv4.z, dv4.w};
        float ww = wsm[r];
#pragma unroll
        for (int e = 0; e < 4; ++e) {
            int cc = c + e;
            bool isdiag = (rr == (cc & 4095));
            float gm = fmaxf(0.05f + dv[e] - dd[e], 0.0f);
            float wv = isdiag ? 0.0f : av[e] * ww;
            nacc[e] += wv * gm;
            dacc[e] += wv;
        }
    }
#pragma unroll
    for (int e = 0; e < 4; ++e) {
        atomicAdd(&numb[c + e], nacc[e]);
        atomicAdd(&denb[c + e], dacc[e]);
    }
}
__global__ __launch_bounds__(BLK) void k_fb_epi2fin(const float* __restrict__ numb,
                                                    const float* __restrict__ denb,
                                                    float* __restrict__ out) {
    int c = blockIdx.x * BLK + threadIdx.x;
    float v = numb[c] / denb[c];
    __shared__ float sm[4];
#pragma unroll
    for (int o = 32; o; o >>= 1) v += __shfl_down(v, o);
    if ((threadIdx.x & 63) == 0) sm[threadIdx.x >> 6] = v;
    __syncthreads();
    if (threadIdx.x == 0) atomicAdd(out, sm[0] + sm[1] + sm[2] + sm[3]);
}

// ---------------------------------------------------------------------------
extern "C" void kernel_launch(void* const* d_in, const int* in_sizes, int n_in,
                              void* d_out, int out_size, void* d_ws, size_t ws_size,
                              hipStream_t stream) {
    const float* dist = (const float*)d_in[0];
    float* out = (float*)d_out;

    unsigned short* M  = (unsigned short*)d_ws;                 // 64 MB
    unsigned short* MT = M + (size_t)NR * NC;                   // 64 MB
    unsigned short* wrowH = MT + (size_t)NR * NC;   // 4096 bf16
    unsigned short* wcolH = wrowH + NR;             // 8192 bf16
    float* fb   = (float*)(wcolH + NC);
    float* wrowF = fb;                // 4096 f32 (fallback)
    float* wcolF = wrowF + NR;        // 8192
    float* rm1  = wcolF + NC;         // 4096
    int*   arg1 = (int*)(rm1 + NR);   // 4096
    float* d12  = (float*)(arg1 + NR);// 8192
    float* numb = d12 + NC;           // 8192
    float* denb = numb + NC;          // 8192
    unsigned int* ctrs = (unsigned int*)(denb + NC);   // 64 counters * 16 u32
    unsigned int* rel  = ctrs + 64 * 16;               // release flag

    const unsigned int SMEM = 16512;

    // ---- cooperative persistent kernel with adaptive pow2 grid ----
    int dev = 0;
    (void)hipGetDevice(&dev);
    int numCU = 0;
    (void)hipDeviceGetAttribute(&numCU, hipDeviceAttributeMultiprocessorCount, dev);
    int maxPerCU = 0;
    (void)hipOccupancyMaxActiveBlocksPerMultiprocessor(&maxPerCU, (const void*)k_main,
                                                       BLK, SMEM);
    hipError_t rc = hipErrorUnknown;
    int cand = (numCU > 0 && maxPerCU > 0) ? maxPerCU * numCU : 0;
    if (cand > 2048) cand = 2048;
    int grid = 0;
    if (cand >= 128) { grid = 128; while (grid * 2 <= cand) grid *= 2; }
    if (grid > 0) {
        (void)hipMemsetAsync(ctrs, 0, (64 * 16 + 16) * sizeof(unsigned int), stream);
        void* args[] = {(void*)&dist, (void*)&out, (void*)&M, (void*)&MT,
                        (void*)&wrowH, (void*)&wcolH, (void*)&rm1, (void*)&arg1,
                        (void*)&d12, (void*)&numb, (void*)&denb,
                        (void*)&ctrs, (void*)&rel};
        for (int g = grid; g >= 128 && rc != hipSuccess; g >>= 1) {
            rc = hipLaunchCooperativeKernel((void*)k_main, dim3(g), dim3(BLK),
                                            args, SMEM, stream);
            if (rc != hipSuccess) (void)hipGetLastError();   // clear sticky error
        }
    }
    if (rc == hipSuccess) return;

    // ---- fallback: multi-kernel graph path (guaranteed) ----
    k_fb_init<<<32, BLK, 0, stream>>>(dist, rm1, arg1, d12, wrowF, out);
    k_fb_build1<<<16384, BLK, 0, stream>>>(dist, rm1, M);
    k_fb_transp<<<8192, BLK, 0, stream>>>(M, MT);
    for (int it = 0; it < 50; ++it) {
        k_fb_matvec<NR><<<2048, BLK, 0, stream>>>(MT, wrowF, wcolF, INV8192);
        if (it == 49) break;
        k_fb_matvec<NC><<<1024, BLK, 0, stream>>>(M, wcolF, wrowF, INV4096);
    }
    k_fb_epi1<<<1024, BLK, 0, stream>>>(M, dist, wcolF, rm1, arg1, out);

    k_fb_build2<<<16384, BLK, 0, stream>>>(dist, d12, M);
    k_fb_init2<<<32, BLK, 0, stream>>>(wcolF, numb, denb);
    k_fb_transp<<<8192, BLK, 0, stream>>>(M, MT);
    for (int it = 0; it < 50; ++it) {
        k_fb_matvec<NC><<<1024, BLK, 0, stream>>>(M, wcolF, wrowF, INV4096);
        if (it == 49) break;
        k_fb_matvec<NR><<<2048, BLK, 0, stream>>>(MT, wrowF, wcolF, INV8192);
    }
    k_fb_epi2<<<512, BLK, 0, stream>>>(M, dist, wrowF, d12, numb, denb);
    k_fb_epi2fin<<<32, BLK, 0, stream>>>(numb, denb, out);
}

// Round 8
// 3444.651 us; speedup vs baseline: 1.1187x; 1.1187x over previous
//
#include <hip/hip_runtime.h>
#include <hip/hip_cooperative_groups.h>
#include <math.h>

namespace cg = cooperative_groups;

#define DC 8220      // dist row stride (28 + 8192)
#define OFF 28
#define NR 4096      // rows of M8 (loss1: K1; loss2: K2^T)
#define NC 8192      // cols of M8
#define INV4096 (1.0f / 4096.0f)
#define INV8192 (1.0f / 8192.0f)
#define BLK 256

#define AGENT __HIP_MEMORY_SCOPE_AGENT

#if defined(__has_builtin)
#if __has_builtin(__builtin_amdgcn_cvt_pk_f32_fp8) && __has_builtin(__builtin_amdgcn_cvt_pk_fp8_f32)
#define HAVE_FP8_CVT 1
#endif
#endif
#ifndef HAVE_FP8_CVT
#define HAVE_FP8_CVT 0
#endif

typedef float floatx2 __attribute__((ext_vector_type(2)));

__device__ __forceinline__ float bflo(unsigned int u) { return __uint_as_float(u << 16); }
__device__ __forceinline__ float bfhi(unsigned int u) { return __uint_as_float(u & 0xffff0000u); }
__device__ __forceinline__ unsigned short f2bf(float f) {
    unsigned int i = __float_as_uint(f);
    return (unsigned short)((i + 0x7fffu + ((i >> 16) & 1u)) >> 16);   // RNE
}
__device__ __forceinline__ void st_wbf(unsigned short* p, float v) {
    __hip_atomic_store(p, f2bf(v), __ATOMIC_RELAXED, AGENT);
}
__device__ __forceinline__ float ld_wbf(const unsigned short* p) {
    unsigned short u = __hip_atomic_load(p, __ATOMIC_RELAXED, AGENT);
    return __uint_as_float(((unsigned int)u) << 16);
}

// ---------------- fp8 e4m3 pack/unpack (HW cvt or SW fallback) -------------
#if !HAVE_FP8_CVT
__device__ __forceinline__ float fp8dec_sw(unsigned int b) {
    unsigned int e = (b >> 3) & 0xFu, m = b & 7u;
    float mag = (e == 0) ? (float)m * 0.001953125f
                         : __uint_as_float(((e + 120u) << 23) | (m << 20));
    return (b & 0x80u) ? -mag : mag;
}
__device__ __forceinline__ unsigned int fp8enc_sw(float v) {
    if (v <= 0.0f) return 0u;
    if (v < 0.015625f) return (unsigned int)rintf(v * 512.0f) & 7u;
    int e; float fr = frexpf(v, &e);
    float q = rintf(fr * 16.0f);
    if (q >= 16.0f) { q = 8.0f; ++e; }
    return (((unsigned int)(e + 6) & 0xFu) << 3) | ((unsigned int)q & 7u);
}
#endif

__device__ __forceinline__ unsigned int pk4_fp8(float e0, float e1, float e2, float e3) {
#if HAVE_FP8_CVT
    int v = __builtin_amdgcn_cvt_pk_fp8_f32(e0, e1, 0, false);
    v = __builtin_amdgcn_cvt_pk_fp8_f32(e2, e3, v, true);
    return (unsigned int)v;
#else
    return fp8enc_sw(e0) | (fp8enc_sw(e1) << 8) | (fp8enc_sw(e2) << 16) | (fp8enc_sw(e3) << 24);
#endif
}
__device__ __forceinline__ void fp8x4_to_f32(unsigned int u, float* f) {
#if HAVE_FP8_CVT
    floatx2 p = __builtin_amdgcn_cvt_pk_f32_fp8((int)u, false);
    f[0] = p.x; f[1] = p.y;
    p = __builtin_amdgcn_cvt_pk_f32_fp8((int)u, true);
    f[2] = p.x; f[3] = p.y;
#else
    f[0] = fp8dec_sw(u & 0xffu);
    f[1] = fp8dec_sw((u >> 8) & 0xffu);
    f[2] = fp8dec_sw((u >> 16) & 0xffu);
    f[3] = fp8dec_sw((u >> 24) & 0xffu);
#endif
}

// --------------- tree grid barrier (multi-word release) --------------------
__device__ __forceinline__ void gbar(unsigned int* ctrs, unsigned int* rel,
                                     unsigned int phase, int bid, int cpl) {
    __syncthreads();
    if (threadIdx.x == 0) {
        asm volatile("s_waitcnt vmcnt(0)" ::: "memory");   // drain prior stores
        __hip_atomic_fetch_add(&ctrs[(bid & 63) * 16], 1u, __ATOMIC_RELAXED, AGENT);
    }
    if (bid == 0) {
        if (threadIdx.x < 64) {
            unsigned int tgt = phase * (unsigned int)cpl;
            while (__hip_atomic_load(&ctrs[threadIdx.x * 16], __ATOMIC_RELAXED, AGENT) < tgt)
                __builtin_amdgcn_s_sleep(2);
        }
        __syncthreads();
        if (threadIdx.x < 64)
            __hip_atomic_store(&rel[threadIdx.x * 16], phase, __ATOMIC_RELAXED, AGENT);
    } else if (threadIdx.x == 0) {
        while (__hip_atomic_load(&rel[(bid & 63) * 16], __ATOMIC_RELAXED, AGENT) < phase)
            __builtin_amdgcn_s_sleep(2);
    }
    __syncthreads();
}

// stage n bf16 weights (coherent) into LDS (contiguous, 8B granules)
__device__ __forceinline__ void stage_hbf(const unsigned short* __restrict__ wbf,
                                          unsigned long long* lds64, int nelem, int tid) {
    for (int g = tid; g < (nelem >> 2); g += BLK)
        lds64[g] = __hip_atomic_load((const unsigned long long*)wbf + g,
                                     __ATOMIC_RELAXED, AGENT);
    __syncthreads();
}

// W-wide fp8 row dot with bf16 weights in LDS; lane0 holds result
template <int W>
__device__ __forceinline__ float dot_fp8(const unsigned char* __restrict__ row,
                                         const uint4* vv4, int lane) {
    float acc = 0.0f;
#pragma unroll
    for (int k = 0; k < W / 1024; ++k) {
        int j = k * 1024 + lane * 8;
#pragma unroll
        for (int h = 0; h < 2; ++h) {
            uint2 a = *(const uint2*)(row + j + h * 512);
            uint4 w = vv4[k * 128 + h * 64 + lane];
            float f[8];
            fp8x4_to_f32(a.x, f);
            fp8x4_to_f32(a.y, f + 4);
            acc = fmaf(f[0], bflo(w.x), acc);
            acc = fmaf(f[1], bfhi(w.x), acc);
            acc = fmaf(f[2], bflo(w.y), acc);
            acc = fmaf(f[3], bfhi(w.y), acc);
            acc = fmaf(f[4], bflo(w.z), acc);
            acc = fmaf(f[5], bfhi(w.z), acc);
            acc = fmaf(f[6], bflo(w.w), acc);
            acc = fmaf(f[7], bfhi(w.w), acc);
        }
    }
#pragma unroll
    for (int o = 32; o; o >>= 1) acc += __shfl_down(acc, o);
    return acc;
}

// ---------------- fp8 builders + byte transpose -----------------------------
__device__ __forceinline__ void build1_fp8(const float* __restrict__ dist,
                                           const float* __restrict__ rm1,
                                           unsigned char* __restrict__ M8, int c) {
    int i = c >> 10;
    int j = (c & 1023) << 3;
    float rm = rm1[i];
    const float* Dr = dist + (size_t)i * DC + OFF + j;
    float4 d0 = *(const float4*)Dr;
    float4 d1 = *(const float4*)(Dr + 4);
    float dv[8] = {d0.x, d0.y, d0.z, d0.w, d1.x, d1.y, d1.z, d1.w};
    float e[8];
#pragma unroll
    for (int k = 0; k < 8; ++k) {
        int jj = j + k;
        bool diag = (jj == i) || (jj == i + 4096);
        float gm = diag ? 0.0f : fmaxf(0.05f + dv[k] - rm, 0.0f);
        e[k] = __expf(5.0f * __expf(-gm));
    }
    uint2 o;
    o.x = pk4_fp8(e[0], e[1], e[2], e[3]);
    o.y = pk4_fp8(e[4], e[5], e[6], e[7]);
    *(uint2*)(M8 + (size_t)c * 8) = o;
}
__device__ __forceinline__ void build2_fp8(const float* __restrict__ dist,
                                           const float* __restrict__ d12,
                                           unsigned char* __restrict__ M8, int c) {
    int r = c >> 10;
    int col = (c & 1023) << 3;
    const float* Dr = dist + (size_t)r * DC + OFF + col;
    float4 d0 = *(const float4*)Dr;
    float4 d1 = *(const float4*)(Dr + 4);
    float4 e0 = *(const float4*)(d12 + col);
    float4 e1 = *(const float4*)(d12 + col + 4);
    float dv[8] = {d0.x, d0.y, d0.z, d0.w, d1.x, d1.y, d1.z, d1.w};
    float dd[8] = {e0.x, e0.y, e0.z, e0.w, e1.x, e1.y, e1.z, e1.w};
    float e[8];
#pragma unroll
    for (int k = 0; k < 8; ++k) {
        int cc = col + k;
        bool diag = (r == (cc & 4095));
        float gm = diag ? 0.0f : fmaxf(0.05f + dv[k] - dd[k], 0.0f);
        e[k] = __expf(5.0f * __expf(-gm));
    }
    uint2 o;
    o.x = pk4_fp8(e[0], e[1], e[2], e[3]);
    o.y = pk4_fp8(e[4], e[5], e[6], e[7]);
    *(uint2*)(M8 + (size_t)c * 8) = o;
}

// 64x64 byte tile transpose: S (4096x8192) -> D (8192x4096); t in [0,8192)
__device__ __forceinline__ void tile_transpose8(const unsigned char* __restrict__ S,
                                                unsigned char* __restrict__ D,
                                                unsigned int (*t32)[17], int t, int tid) {
    int r0 = (t >> 7) * 64;
    int c0 = (t & 127) * 64;
    int rr = tid >> 2, lc = tid & 3;
    uint4 a = *(const uint4*)(S + (size_t)(r0 + rr) * NC + c0 + lc * 16);
    t32[rr][lc * 4 + 0] = a.x;
    t32[rr][lc * 4 + 1] = a.y;
    t32[rr][lc * 4 + 2] = a.z;
    t32[rr][lc * 4 + 3] = a.w;
    __syncthreads();
    int cc = tid >> 2, seg = tid & 3;
    unsigned int o[4];
#pragma unroll
    for (int q4 = 0; q4 < 4; ++q4) {
        unsigned int v = 0;
#pragma unroll
        for (int b = 0; b < 4; ++b) {
            int srow = seg * 16 + q4 * 4 + b;
            unsigned int w = t32[srow][cc >> 2];
            v |= ((w >> ((cc & 3) * 8)) & 0xffu) << (b * 8);
        }
        o[q4] = v;
    }
    *(uint4*)(D + (size_t)(c0 + cc) * NR + r0 + seg * 16) = make_uint4(o[0], o[1], o[2], o[3]);
    __syncthreads();
}

// ------------------------- cooperative persistent kernel -------------------
__global__ __launch_bounds__(BLK, 4) void k_main(const float* __restrict__ dist,
                                                 float* __restrict__ out,
                                                 unsigned char* __restrict__ M8,
                                                 unsigned char* __restrict__ MT8,
                                                 unsigned short* __restrict__ wrowH,
                                                 unsigned short* __restrict__ wcolH,
                                                 float* __restrict__ rm1,
                                                 int* __restrict__ arg1,
                                                 float* __restrict__ d12,
                                                 float* __restrict__ numb,
                                                 float* __restrict__ denb,
                                                 unsigned int* __restrict__ ctrs,
                                                 unsigned int* __restrict__ rel) {
    cg::grid_group grid = cg::this_grid();
    const int tid = threadIdx.x, bid = blockIdx.x;
    const int nb = gridDim.x, nt = nb * BLK;
    const int gt = bid * BLK + tid;
    const int nw = nt >> 6, wave = gt >> 6, lane = tid & 63;
    const int cpl = nb >> 6;
    unsigned int pc = 0;

    extern __shared__ char smem[];                        // 16512 B
    unsigned long long* lds64 = (unsigned long long*)smem;
    const uint4* vv4 = (const uint4*)smem;
    unsigned int (*tile)[17] = (unsigned int(*)[17])smem;
    float* wsm = (float*)smem;

    // ---------------- init ----------------
    for (int t = gt; t < NC; t += nt) {
        if (t == 0) __hip_atomic_store(out, 0.0f, __ATOMIC_RELAXED, AGENT);
        if (t < NR) {
            float a = dist[(size_t)t * DC + OFF + t];
            float b = dist[(size_t)t * DC + OFF + 4096 + t];
            rm1[t] = fmaxf(a, b);
            arg1[t] = (a >= b) ? t : t + 4096;             // first max wins
            st_wbf(&wrowH[t], INV4096);                    // exact in bf16
        }
        d12[t] = dist[(size_t)(t & 4095) * DC + OFF + t];
    }
    grid.sync();
    for (int c = gt; c < NR * NC / 8; c += nt) build1_fp8(dist, rm1, M8, c);
    grid.sync();
    for (int t = bid; t < 8192; t += nb) tile_transpose8(M8, MT8, tile, t, tid);
    grid.sync();

    // ---------------- loss1 Sinkhorn ----------------
    for (int it = 0; it < 50; ++it) {
        stage_hbf(wrowH, lds64, NR, tid);                  // 8 KB
        for (int r = wave; r < NC; r += nw) {
            float s = dot_fp8<4096>(MT8 + (size_t)r * NR, vv4, lane);
            if (lane == 0) st_wbf(&wcolH[r], __fdividef(INV8192, s));
        }
        gbar(ctrs, rel, ++pc, bid, cpl);
        if (it == 49) break;                               // last wrow dead
        stage_hbf(wcolH, lds64, NC, tid);                  // 16 KB
        for (int i = wave; i < NR; i += nw) {
            float s = dot_fp8<8192>(M8 + (size_t)i * NC, vv4, lane);
            if (lane == 0) st_wbf(&wrowH[i], __fdividef(INV4096, s));
        }
        gbar(ctrs, rel, ++pc, bid, cpl);
    }

    // ---------------- epi1 (K recomputed in f32) + build2 overlap ----------
    stage_hbf(wcolH, lds64, NC, tid);
    for (int i = wave; i < NR; i += nw) {
        float rm = rm1[i];
        int arg = arg1[i];
        const float* Dr = dist + (size_t)i * DC + OFF;
        float num = 0.0f, den = 0.0f;
#pragma unroll 2
        for (int k = 0; k < 8; ++k) {
            int j = k * 1024 + lane * 8;
#pragma unroll
            for (int h = 0; h < 2; ++h) {
                int jb = j + h * 512;
                float4 d0 = *(const float4*)(Dr + jb);
                float4 d1 = *(const float4*)(Dr + jb + 4);
                uint4 w = vv4[k * 128 + h * 64 + lane];
                float tv[8] = {bflo(w.x), bfhi(w.x), bflo(w.y), bfhi(w.y),
                               bflo(w.z), bfhi(w.z), bflo(w.w), bfhi(w.w)};
                float dv[8] = {d0.x, d0.y, d0.z, d0.w, d1.x, d1.y, d1.z, d1.w};
#pragma unroll
                for (int e = 0; e < 8; ++e) {
                    int jj = jb + e;
                    bool isdiag = (jj == i) || (jj == i + 4096);
                    float goff = fmaxf(0.05f + dv[e] - rm, 0.0f);
                    float K = __expf(5.0f * __expf(-(isdiag ? 0.0f : goff)));
                    float gm = isdiag ? fmaxf(rm - 0.5f - dv[e], 0.0f) : goff;
                    bool keep = (jj != arg) && ((jj < 4096) || (jj == i + 4096));
                    float wv = keep ? K * tv[e] : 0.0f;
                    num += wv * gm;
                    den += wv;
                }
            }
        }
#pragma unroll
        for (int o = 32; o; o >>= 1) {
            num += __shfl_down(num, o);
            den += __shfl_down(den, o);
        }
        if (lane == 0) atomicAdd(out, num / den);
    }
    // build2 can start now: epi1 never reads M8 (recompute), Sinkhorn done
    for (int c = gt; c < NR * NC / 8; c += nt) build2_fp8(dist, d12, M8, c);
    grid.sync();                                           // flush M8 + epi1 staging done

    for (int t = gt; t < NC; t += nt) {
        st_wbf(&wcolH[t], INV8192);                        // u2_0 exact
        __hip_atomic_store(&numb[t], 0.0f, __ATOMIC_RELAXED, AGENT);
        __hip_atomic_store(&denb[t], 0.0f, __ATOMIC_RELAXED, AGENT);
    }
    for (int t = bid; t < 8192; t += nb) tile_transpose8(M8, MT8, tile, t, tid);
    grid.sync();                                           // flush MT8

    // ---------------- loss2 Sinkhorn ----------------
    for (int it = 0; it < 50; ++it) {
        stage_hbf(wcolH, lds64, NC, tid);
        for (int r = wave; r < NR; r += nw) {
            float s = dot_fp8<8192>(M8 + (size_t)r * NC, vv4, lane);
            if (lane == 0) st_wbf(&wrowH[r], __fdividef(INV4096, s));
        }
        gbar(ctrs, rel, ++pc, bid, cpl);
        if (it == 49) break;                               // last wcol dead
        stage_hbf(wrowH, lds64, NR, tid);
        for (int r = wave; r < NC; r += nw) {
            float s = dot_fp8<4096>(MT8 + (size_t)r * NR, vv4, lane);
            if (lane == 0) st_wbf(&wcolH[r], __fdividef(INV8192, s));
        }
        gbar(ctrs, rel, ++pc, bid, cpl);
    }

    // ---------------- epi2 (K2^T recomputed in f32) ----------------
    for (int t = bid; t < 512; t += nb) {
        int r0 = (t >> 3) * 64;
        int c = (t & 7) * 1024 + tid * 4;
        if (tid < 64) wsm[tid] = ld_wbf(&wrowH[r0 + tid]);
        __syncthreads();
        float4 e0 = *(const float4*)(d12 + c);
        float dd[4] = {e0.x, e0.y, e0.z, e0.w};
        float nacc[4] = {0.f, 0.f, 0.f, 0.f};
        float dacc[4] = {0.f, 0.f, 0.f, 0.f};
        for (int r = 0; r < 64; ++r) {
            int rr = r0 + r;
            float4 dv4 = *(const float4*)(dist + (size_t)rr * DC + OFF + c);
            float dv[4] = {dv4.x, dv4.y, dv4.z, dv4.w};
            float ww = wsm[r];
#pragma unroll
            for (int e = 0; e < 4; ++e) {
                int cc = c + e;
                bool isdiag = (rr == (cc & 4095));
                float gm = fmaxf(0.05f + dv[e] - dd[e], 0.0f);
                float K = __expf(5.0f * __expf(-gm));
                float wv = isdiag ? 0.0f : K * ww;
                nacc[e] += wv * gm;
                dacc[e] += wv;
            }
        }
#pragma unroll
        for (int e = 0; e < 4; ++e) {
            atomicAdd(&numb[c + e], nacc[e]);
            atomicAdd(&denb[c + e], dacc[e]);
        }
        __syncthreads();
    }
    gbar(ctrs, rel, ++pc, bid, cpl);
    for (int t = wave; t < 128; t += nw) {
        int c = t * 64 + lane;
        float n = __hip_atomic_load(&numb[c], __ATOMIC_RELAXED, AGENT);
        float d = __hip_atomic_load(&denb[c], __ATOMIC_RELAXED, AGENT);
        float v = n / d;
#pragma unroll
        for (int o = 32; o; o >>= 1) v += __shfl_down(v, o);
        if (lane == 0) atomicAdd(out, v);
    }
}

// ------------------------- fallback multi-kernel path (bf16, proven) -------
__device__ __forceinline__ void fb_build1(const float* __restrict__ dist,
                                          const float* __restrict__ rm1,
                                          unsigned short* __restrict__ M, int c) {
    int i = c >> 10;
    int j = (c & 1023) << 3;
    float rm = rm1[i];
    const float* Dr = dist + (size_t)i * DC + OFF + j;
    float4 d0 = *(const float4*)Dr;
    float4 d1 = *(const float4*)(Dr + 4);
    float dv[8] = {d0.x, d0.y, d0.z, d0.w, d1.x, d1.y, d1.z, d1.w};
    unsigned short e[8];
#pragma unroll
    for (int k = 0; k < 8; ++k) {
        int jj = j + k;
        bool diag = (jj == i) || (jj == i + 4096);
        float gm = diag ? 0.0f : fmaxf(0.05f + dv[k] - rm, 0.0f);
        e[k] = f2bf(__expf(5.0f * __expf(-gm)));
    }
    uint4 o;
    o.x = (unsigned int)e[0] | ((unsigned int)e[1] << 16);
    o.y = (unsigned int)e[2] | ((unsigned int)e[3] << 16);
    o.z = (unsigned int)e[4] | ((unsigned int)e[5] << 16);
    o.w = (unsigned int)e[6] | ((unsigned int)e[7] << 16);
    *(uint4*)(M + (size_t)c * 8) = o;
}
__device__ __forceinline__ void fb_build2(const float* __restrict__ dist,
                                          const float* __restrict__ d12,
                                          unsigned short* __restrict__ M, int c) {
    int r = c >> 10;
    int col = (c & 1023) << 3;
    const float* Dr = dist + (size_t)r * DC + OFF + col;
    float4 d0 = *(const float4*)Dr;
    float4 d1 = *(const float4*)(Dr + 4);
    float4 e0 = *(const float4*)(d12 + col);
    float4 e1 = *(const float4*)(d12 + col + 4);
    float dv[8] = {d0.x, d0.y, d0.z, d0.w, d1.x, d1.y, d1.z, d1.w};
    float dd[8] = {e0.x, e0.y, e0.z, e0.w, e1.x, e1.y, e1.z, e1.w};
    unsigned short e[8];
#pragma unroll
    for (int k = 0; k < 8; ++k) {
        int cc = col + k;
        bool diag = (r == (cc & 4095));
        float gm = diag ? 0.0f : fmaxf(0.05f + dv[k] - dd[k], 0.0f);
        e[k] = f2bf(__expf(5.0f * __expf(-gm)));
    }
    uint4 o;
    o.x = (unsigned int)e[0] | ((unsigned int)e[1] << 16);
    o.y = (unsigned int)e[2] | ((unsigned int)e[3] << 16);
    o.z = (unsigned int)e[4] | ((unsigned int)e[5] << 16);
    o.w = (unsigned int)e[6] | ((unsigned int)e[7] << 16);
    *(uint4*)(M + (size_t)c * 8) = o;
}
__device__ __forceinline__ void fb_transpose(const unsigned short* __restrict__ M,
                                             unsigned short* __restrict__ MT,
                                             unsigned int (*tile)[33], int t, int tid) {
    int r0 = (t >> 7) * 64;
    int c0 = (t & 127) * 64;
    int lc = tid & 7, rr = tid >> 3;
#pragma unroll
    for (int s = 0; s < 2; ++s) {
        int r = rr + s * 32;
        uint4 a = *(const uint4*)(M + (size_t)(r0 + r) * NC + c0 + lc * 8);
        tile[r][lc * 4 + 0] = a.x;
        tile[r][lc * 4 + 1] = a.y;
        tile[r][lc * 4 + 2] = a.z;
        tile[r][lc * 4 + 3] = a.w;
    }
    __syncthreads();
    int cc = tid >> 2, rs = (tid & 3) * 16;
    unsigned int o[8];
#pragma unroll
    for (int w = 0; w < 8; ++w) {
        unsigned int ue = tile[rs + 2 * w][cc >> 1];
        unsigned int uo = tile[rs + 2 * w + 1][cc >> 1];
        unsigned short e = (cc & 1) ? (unsigned short)(ue >> 16) : (unsigned short)(ue & 0xffffu);
        unsigned short d = (cc & 1) ? (unsigned short)(uo >> 16) : (unsigned short)(uo & 0xffffu);
        o[w] = (unsigned int)e | ((unsigned int)d << 16);
    }
    unsigned short* dst = MT + (size_t)(c0 + cc) * NR + r0 + rs;
    *(uint4*)dst = make_uint4(o[0], o[1], o[2], o[3]);
    *(uint4*)(dst + 8) = make_uint4(o[4], o[5], o[6], o[7]);
    __syncthreads();
}
template <int W>
__device__ __forceinline__ float rowdot_g(const unsigned short* __restrict__ row,
                                          const float* __restrict__ w, int lane) {
    float acc = 0.0f;
#pragma unroll
    for (int s = 0; s < W; s += 512) {
        int j = s + lane * 8;
        uint4 a = *(const uint4*)(row + j);
        float4 w0 = *(const float4*)(w + j);
        float4 w1 = *(const float4*)(w + j + 4);
        acc = fmaf(bflo(a.x), w0.x, acc);
        acc = fmaf(bfhi(a.x), w0.y, acc);
        acc = fmaf(bflo(a.y), w0.z, acc);
        acc = fmaf(bfhi(a.y), w0.w, acc);
        acc = fmaf(bflo(a.z), w1.x, acc);
        acc = fmaf(bfhi(a.z), w1.y, acc);
        acc = fmaf(bflo(a.w), w1.z, acc);
        acc = fmaf(bfhi(a.w), w1.w, acc);
    }
#pragma unroll
    for (int o = 32; o; o >>= 1) acc += __shfl_down(acc, o);
    return acc;
}
__global__ __launch_bounds__(BLK) void k_fb_init(const float* __restrict__ dist,
                                                 float* __restrict__ rm1, int* __restrict__ arg1,
                                                 float* __restrict__ d12, float* __restrict__ wrow,
                                                 float* __restrict__ out) {
    int t = blockIdx.x * BLK + threadIdx.x;
    if (t == 0) out[0] = 0.0f;
    if (t < NR) {
        float a = dist[(size_t)t * DC + OFF + t];
        float b = dist[(size_t)t * DC + OFF + 4096 + t];
        rm1[t] = fmaxf(a, b);
        arg1[t] = (a >= b) ? t : t + 4096;
        wrow[t] = INV4096;
    }
    d12[t] = dist[(size_t)(t & 4095) * DC + OFF + t];
}
__global__ __launch_bounds__(BLK) void k_fb_build1(const float* __restrict__ dist,
                                                   const float* __restrict__ rm1,
                                                   unsigned short* __restrict__ M) {
    fb_build1(dist, rm1, M, blockIdx.x * BLK + threadIdx.x);
}
__global__ __launch_bounds__(BLK) void k_fb_build2(const float* __restrict__ dist,
                                                   const float* __restrict__ d12,
                                                   unsigned short* __restrict__ M) {
    fb_build2(dist, d12, M, blockIdx.x * BLK + threadIdx.x);
}
__global__ __launch_bounds__(BLK) void k_fb_transp(const unsigned short* __restrict__ M,
                                                   unsigned short* __restrict__ MT) {
    __shared__ unsigned int tile[64][33];
    fb_transpose(M, MT, tile, blockIdx.x, threadIdx.x);
}
template <int W>
__global__ __launch_bounds__(BLK) void k_fb_matvec(const unsigned short* __restrict__ Mat,
                                                   const float* __restrict__ w,
                                                   float* __restrict__ outv, float scale) {
    int r = blockIdx.x * 4 + (threadIdx.x >> 6);
    float s = rowdot_g<W>(Mat + (size_t)r * W, w, threadIdx.x & 63);
    if ((threadIdx.x & 63) == 0) outv[r] = __fdividef(scale, s);
}
__global__ __launch_bounds__(BLK) void k_fb_epi1(const unsigned short* __restrict__ M,
                                                 const float* __restrict__ dist,
                                                 const float* __restrict__ wcol,
                                                 const float* __restrict__ rm1,
                                                 const int* __restrict__ arg1,
                                                 float* __restrict__ out) {
    int i = blockIdx.x * 4 + (threadIdx.x >> 6);
    int lane = threadIdx.x & 63;
    float rm = rm1[i];
    int arg = arg1[i];
    const unsigned short* Ar = M + (size_t)i * NC;
    const float* Dr = dist + (size_t)i * DC + OFF;
    float num = 0.0f, den = 0.0f;
#pragma unroll 4
    for (int s = 0; s < NC; s += 512) {
        int j0 = s + lane * 8;
        uint4 a = *(const uint4*)(Ar + j0);
        float4 t0 = *(const float4*)(wcol + j0);
        float4 t1 = *(const float4*)(wcol + j0 + 4);
        float4 d0 = *(const float4*)(Dr + j0);
        float4 d1 = *(const float4*)(Dr + j0 + 4);
        float av[8] = {bflo(a.x), bfhi(a.x), bflo(a.y), bfhi(a.y),
                       bflo(a.z), bfhi(a.z), bflo(a.w), bfhi(a.w)};
        float tv[8] = {t0.x, t0.y, t0.z, t0.w, t1.x, t1.y, t1.z, t1.w};
        float dv[8] = {d0.x, d0.y, d0.z, d0.w, d1.x, d1.y, d1.z, d1.w};
#pragma unroll
        for (int e = 0; e < 8; ++e) {
            int jj = j0 + e;
            bool isdiag = (jj == i) || (jj == i + 4096);
            float gm = isdiag ? fmaxf(rm - 0.5f - dv[e], 0.0f)
                              : fmaxf(0.05f + dv[e] - rm, 0.0f);
            bool keep = (jj != arg) && ((jj < 4096) || (jj == i + 4096));
            float wv = keep ? av[e] * tv[e] : 0.0f;
            num += wv * gm;
            den += wv;
        }
    }
#pragma unroll
    for (int o = 32; o; o >>= 1) {
        num += __shfl_down(num, o);
        den += __shfl_down(den, o);
    }
    if (lane == 0) atomicAdd(out, num / den);
}
__global__ __launch_bounds__(BLK) void k_fb_init2(float* __restrict__ wcol,
                                                  float* __restrict__ numb,
                                                  float* __restrict__ denb) {
    int t = blockIdx.x * BLK + threadIdx.x;
    wcol[t] = INV8192;
    numb[t] = 0.0f;
    denb[t] = 0.0f;
}
__global__ __launch_bounds__(BLK) void k_fb_epi2(const unsigned short* __restrict__ M,
                                                 const float* __restrict__ dist,
                                                 const float* __restrict__ wrow,
                                                 const float* __restrict__ d12,
                                                 float* __restrict__ numb,
                                                 float* __restrict__ denb) {
    __shared__ float wsm[64];
    int t = blockIdx.x, tid = threadIdx.x;
    int r0 = (t >> 3) * 64;
    int c = (t & 7) * 1024 + tid * 4;
    if (tid < 64) wsm[tid] = wrow[r0 + tid];
    __syncthreads();
    float4 e0 = *(const float4*)(d12 + c);
    float dd[4] = {e0.x, e0.y, e0.z, e0.w};
    float nacc[4] = {0.f, 0.f, 0.f, 0.f};
    float dacc[4] = {0.f, 0.f, 0.f, 0.f};
    for (int r = 0; r < 64; ++r) {
        int rr = r0 + r;
        uint2 a = *(const uint2*)(M + (size_t)rr * NC + c);
        float4 dv4 = *(const float4*)(dist + (size_t)rr * DC + OFF + c);
        float av[4] = {bflo(a.x), bfhi(a.x), bflo(a.y), bfhi(a.y)};
        float dv[4] = {dv4.x, dv4.y, dv4.z, dv4.w};
        float ww = wsm[r];
#pragma unroll
        for (int e = 0; e < 4; ++e) {
            int cc = c + e;
            bool isdiag = (rr == (cc & 4095));
            float gm = fmaxf(0.05f + dv[e] - dd[e], 0.0f);
            float wv = isdiag ? 0.0f : av[e] * ww;
            nacc[e] += wv * gm;
            dacc[e] += wv;
        }
    }
#pragma unroll
    for (int e = 0; e < 4; ++e) {
        atomicAdd(&numb[c + e], nacc[e]);
        atomicAdd(&denb[c + e], dacc[e]);
    }
}
__global__ __launch_bounds__(BLK) void k_fb_epi2fin(const float* __restrict__ numb,
                                                    const float* __restrict__ denb,
                                                    float* __restrict__ out) {
    int c = blockIdx.x * BLK + threadIdx.x;
    float v = numb[c] / denb[c];
    __shared__ float sm[4];
#pragma unroll
    for (int o = 32; o; o >>= 1) v += __shfl_down(v, o);
    if ((threadIdx.x & 63) == 0) sm[threadIdx.x >> 6] = v;
    __syncthreads();
    if (threadIdx.x == 0) atomicAdd(out, sm[0] + sm[1] + sm[2] + sm[3]);
}

// ---------------------------------------------------------------------------
extern "C" void kernel_launch(void* const* d_in, const int* in_sizes, int n_in,
                              void* d_out, int out_size, void* d_ws, size_t ws_size,
                              hipStream_t stream) {
    const float* dist = (const float*)d_in[0];
    float* out = (float*)d_out;

    // main path: fp8 matrices overlay the front of ws
    unsigned char* M8  = (unsigned char*)d_ws;                  // 33.5 MB
    unsigned char* MT8 = M8 + (size_t)NR * NC;                  // 33.5 MB
    // fallback path: bf16 matrices overlay the same region
    unsigned short* Mfb  = (unsigned short*)d_ws;               // 64 MB
    unsigned short* MTfb = Mfb + (size_t)NR * NC;               // 64 MB
    // aux region beyond 128 MB
    unsigned short* wrowH = (unsigned short*)((char*)d_ws + (size_t)NR * NC * 4);
    unsigned short* wcolH = wrowH + NR;
    float* fbf   = (float*)(wcolH + NC);
    float* wrowF = fbf;
    float* wcolF = wrowF + NR;
    float* rm1  = wcolF + NC;
    int*   arg1 = (int*)(rm1 + NR);
    float* d12  = (float*)(arg1 + NR);
    float* numb = d12 + NC;
    float* denb = numb + NC;
    unsigned int* ctrs = (unsigned int*)(denb + NC);   // 64*16 u32
    unsigned int* rel  = ctrs + 64 * 16;               // 64*16 u32

    const unsigned int SMEM = 16512;

    int dev = 0;
    (void)hipGetDevice(&dev);
    int numCU = 0;
    (void)hipDeviceGetAttribute(&numCU, hipDeviceAttributeMultiprocessorCount, dev);
    int maxPerCU = 0;
    (void)hipOccupancyMaxActiveBlocksPerMultiprocessor(&maxPerCU, (const void*)k_main,
                                                       BLK, SMEM);
    hipError_t rc = hipErrorUnknown;
    int cand = (numCU > 0 && maxPerCU > 0) ? maxPerCU * numCU : 0;
    if (cand > 1024) cand = 1024;                       // 4/CU measured best
    int grid = 0;
    if (cand >= 128) { grid = 128; while (grid * 2 <= cand) grid *= 2; }
    if (grid > 0) {
        (void)hipMemsetAsync(ctrs, 0, 2 * 64 * 16 * sizeof(unsigned int), stream);
        void* args[] = {(void*)&dist, (void*)&out, (void*)&M8, (void*)&MT8,
                        (void*)&wrowH, (void*)&wcolH, (void*)&rm1, (void*)&arg1,
                        (void*)&d12, (void*)&numb, (void*)&denb,
                        (void*)&ctrs, (void*)&rel};
        for (int g = grid; g >= 128 && rc != hipSuccess; g >>= 1) {
            rc = hipLaunchCooperativeKernel((void*)k_main, dim3(g), dim3(BLK),
                                            args, SMEM, stream);
            if (rc != hipSuccess) (void)hipGetLastError();
        }
    }
    if (rc == hipSuccess) return;

    // ---- fallback: multi-kernel graph path (guaranteed) ----
    k_fb_init<<<32, BLK, 0, stream>>>(dist, rm1, arg1, d12, wrowF, out);
    k_fb_build1<<<16384, BLK, 0, stream>>>(dist, rm1, Mfb);
    k_fb_transp<<<8192, BLK, 0, stream>>>(Mfb, MTfb);
    for (int it = 0; it < 50; ++it) {
        k_fb_matvec<NR><<<2048, BLK, 0, stream>>>(MTfb, wrowF, wcolF, INV8192);
        if (it == 49) break;
        k_fb_matvec<NC><<<1024, BLK, 0, stream>>>(Mfb, wcolF, wrowF, INV4096);
    }
    k_fb_epi1<<<1024, BLK, 0, stream>>>(Mfb, dist, wcolF, rm1, arg1, out);

    k_fb_build2<<<16384, BLK, 0, stream>>>(dist, d12, Mfb);
    k_fb_init2<<<32, BLK, 0, stream>>>(wcolF, numb, denb);
    k_fb_transp<<<8192, BLK, 0, stream>>>(Mfb, MTfb);
    for (int it = 0; it < 50; ++it) {
        k_fb_matvec<NC><<<1024, BLK, 0, stream>>>(Mfb, wcolF, wrowF, INV4096);
        if (it == 49) break;
        k_fb_matvec<NR><<<2048, BLK, 0, stream>>>(MTfb, wrowF, wcolF, INV8192);
    }
    k_fb_epi2<<<512, BLK, 0, stream>>>(Mfb, dist, wrowF, d12, numb, denb);
    k_fb_epi2fin<<<32, BLK, 0, stream>>>(numb, denb, out);
}

// Round 9
// 1969.734 us; speedup vs baseline: 1.9564x; 1.7488x over previous
//
#include <hip/hip_runtime.h>
#include <hip/hip_cooperative_groups.h>
#include <math.h>

namespace cg = cooperative_groups;

#define DC 8220      // dist row stride (28 + 8192)
#define OFF 28
#define NR 4096
#define NC 8192
#define INV4096 (1.0f / 4096.0f)
#define INV8192 (1.0f / 8192.0f)
#define BLK 256

#define AGENT __HIP_MEMORY_SCOPE_AGENT
typedef unsigned long long ull;

#if defined(__has_builtin)
#if __has_builtin(__builtin_amdgcn_cvt_pk_f32_fp8) && __has_builtin(__builtin_amdgcn_cvt_pk_fp8_f32)
#define HAVE_FP8_CVT 1
#endif
#endif
#ifndef HAVE_FP8_CVT
#define HAVE_FP8_CVT 0
#endif

typedef float floatx2 __attribute__((ext_vector_type(2)));

__device__ __forceinline__ float bflo(unsigned int u) { return __uint_as_float(u << 16); }
__device__ __forceinline__ float bfhi(unsigned int u) { return __uint_as_float(u & 0xffff0000u); }
__device__ __forceinline__ unsigned short f2bf(float f) {
    unsigned int i = __float_as_uint(f);
    return (unsigned short)((i + 0x7fffu + ((i >> 16) & 1u)) >> 16);   // RNE
}
__device__ __forceinline__ void st_wbf(unsigned short* p, float v) {
    __hip_atomic_store(p, f2bf(v), __ATOMIC_RELAXED, AGENT);
}
__device__ __forceinline__ float ld_wbf(const unsigned short* p) {
    unsigned short u = __hip_atomic_load(p, __ATOMIC_RELAXED, AGENT);
    return __uint_as_float(((unsigned int)u) << 16);
}

// ---------------- fp8 e4m3 pack/unpack ------------------------------------
#if !HAVE_FP8_CVT
__device__ __forceinline__ float fp8dec_sw(unsigned int b) {
    unsigned int e = (b >> 3) & 0xFu, m = b & 7u;
    float mag = (e == 0) ? (float)m * 0.001953125f
                         : __uint_as_float(((e + 120u) << 23) | (m << 20));
    return (b & 0x80u) ? -mag : mag;
}
__device__ __forceinline__ unsigned int fp8enc_sw(float v) {
    if (v <= 0.0f) return 0u;
    if (v < 0.015625f) return (unsigned int)rintf(v * 512.0f) & 7u;
    int e; float fr = frexpf(v, &e);
    float q = rintf(fr * 16.0f);
    if (q >= 16.0f) { q = 8.0f; ++e; }
    return (((unsigned int)(e + 6) & 0xFu) << 3) | ((unsigned int)q & 7u);
}
#endif
__device__ __forceinline__ unsigned int pk4_fp8(float e0, float e1, float e2, float e3) {
#if HAVE_FP8_CVT
    int v = __builtin_amdgcn_cvt_pk_fp8_f32(e0, e1, 0, false);
    v = __builtin_amdgcn_cvt_pk_fp8_f32(e2, e3, v, true);
    return (unsigned int)v;
#else
    return fp8enc_sw(e0) | (fp8enc_sw(e1) << 8) | (fp8enc_sw(e2) << 16) | (fp8enc_sw(e3) << 24);
#endif
}
__device__ __forceinline__ void fp8x4_to_f32(unsigned int u, float* f) {
#if HAVE_FP8_CVT
    floatx2 p = __builtin_amdgcn_cvt_pk_f32_fp8((int)u, false);
    f[0] = p.x; f[1] = p.y;
    p = __builtin_amdgcn_cvt_pk_f32_fp8((int)u, true);
    f[2] = p.x; f[3] = p.y;
#else
    f[0] = fp8dec_sw(u & 0xffu);
    f[1] = fp8dec_sw((u >> 8) & 0xffu);
    f[2] = fp8dec_sw((u >> 16) & 0xffu);
    f[3] = fp8dec_sw((u >> 24) & 0xffu);
#endif
}

// --------------- tree grid barrier (multi-word release) --------------------
__device__ __forceinline__ void gbar(unsigned int* ctrs, unsigned int* rel,
                                     unsigned int phase, int bid, int cpl) {
    __syncthreads();
    if (threadIdx.x == 0) {
        asm volatile("s_waitcnt vmcnt(0)" ::: "memory");
        __hip_atomic_fetch_add(&ctrs[(bid & 63) * 16], 1u, __ATOMIC_RELAXED, AGENT);
    }
    if (bid == 0) {
        if (threadIdx.x < 64) {
            unsigned int tgt = phase * (unsigned int)cpl;
            while (__hip_atomic_load(&ctrs[threadIdx.x * 16], __ATOMIC_RELAXED, AGENT) < tgt)
                __builtin_amdgcn_s_sleep(2);
        }
        __syncthreads();
        if (threadIdx.x < 64)
            __hip_atomic_store(&rel[threadIdx.x * 16], phase, __ATOMIC_RELAXED, AGENT);
    } else if (threadIdx.x == 0) {
        while (__hip_atomic_load(&rel[(bid & 63) * 16], __ATOMIC_RELAXED, AGENT) < phase)
            __builtin_amdgcn_s_sleep(2);
    }
    __syncthreads();
}

// ---- LDS weight slotting: slot(s8) groups 16 elems contiguously so the hot
// dot reads are lane-stride-16B (round-8-proven pattern). s8 = elemIndex>>3.
__device__ __forceinline__ int wslot(int s8) {
    return (s8 >> 7) * 128 + (s8 & 1) * 64 + ((s8 & 127) >> 1);
}

// stage wQ (8192 bf16 -> slots [0,1024)) and wP (4096 bf16 -> slots [1024,1536))
__device__ __forceinline__ void stage2(const unsigned short* __restrict__ wQ,
                                       const unsigned short* __restrict__ wP,
                                       ull* lds, int tid) {
    for (int g = tid; g < 2048; g += BLK) {
        ull v = __hip_atomic_load((const ull*)wQ + g, __ATOMIC_RELAXED, AGENT);
        lds[wslot(g >> 1) * 2 + (g & 1)] = v;
    }
    for (int g = tid; g < 1024; g += BLK) {
        ull v = __hip_atomic_load((const ull*)wP + g, __ATOMIC_RELAXED, AGENT);
        lds[(1024 + wslot(g >> 1)) * 2 + (g & 1)] = v;
    }
    __syncthreads();
}

// 8192-wide fp8 row dot, weights in LDS slots [0,1024)
__device__ __forceinline__ float dotQ(const unsigned char* __restrict__ row,
                                      const uint4* __restrict__ W, int lane) {
    float acc = 0.0f;
#pragma unroll
    for (int c = 0; c < 8; ++c) {
        uint4 a = *(const uint4*)(row + c * 1024 + lane * 16);
        uint4 w0 = W[c * 128 + lane];
        uint4 w1 = W[c * 128 + 64 + lane];
        float f[16];
        fp8x4_to_f32(a.x, f);
        fp8x4_to_f32(a.y, f + 4);
        fp8x4_to_f32(a.z, f + 8);
        fp8x4_to_f32(a.w, f + 12);
        acc = fmaf(f[0], bflo(w0.x), acc);  acc = fmaf(f[1], bfhi(w0.x), acc);
        acc = fmaf(f[2], bflo(w0.y), acc);  acc = fmaf(f[3], bfhi(w0.y), acc);
        acc = fmaf(f[4], bflo(w0.z), acc);  acc = fmaf(f[5], bfhi(w0.z), acc);
        acc = fmaf(f[6], bflo(w0.w), acc);  acc = fmaf(f[7], bfhi(w0.w), acc);
        acc = fmaf(f[8], bflo(w1.x), acc);  acc = fmaf(f[9], bfhi(w1.x), acc);
        acc = fmaf(f[10], bflo(w1.y), acc); acc = fmaf(f[11], bfhi(w1.y), acc);
        acc = fmaf(f[12], bflo(w1.z), acc); acc = fmaf(f[13], bfhi(w1.z), acc);
        acc = fmaf(f[14], bflo(w1.w), acc); acc = fmaf(f[15], bfhi(w1.w), acc);
    }
#pragma unroll
    for (int o = 32; o; o >>= 1) acc += __shfl_down(acc, o);
    return acc;
}

// dual 4096-wide fp8 row dot, weights in LDS slots [1024,1536)
__device__ __forceinline__ void dotP2(const unsigned char* __restrict__ r0,
                                      const unsigned char* __restrict__ r1,
                                      const uint4* __restrict__ W, int lane,
                                      float& o0, float& o1) {
    float a0 = 0.0f, a1 = 0.0f;
#pragma unroll
    for (int c = 0; c < 4; ++c) {
        uint4 a = *(const uint4*)(r0 + c * 1024 + lane * 16);
        uint4 b = *(const uint4*)(r1 + c * 1024 + lane * 16);
        uint4 w0 = W[c * 128 + lane];
        uint4 w1 = W[c * 128 + 64 + lane];
        float fa[16], fb[16];
        fp8x4_to_f32(a.x, fa);  fp8x4_to_f32(a.y, fa + 4);
        fp8x4_to_f32(a.z, fa + 8); fp8x4_to_f32(a.w, fa + 12);
        fp8x4_to_f32(b.x, fb);  fp8x4_to_f32(b.y, fb + 4);
        fp8x4_to_f32(b.z, fb + 8); fp8x4_to_f32(b.w, fb + 12);
        float wv[8] = {bflo(w0.x), bfhi(w0.x), bflo(w0.y), bfhi(w0.y),
                       bflo(w0.z), bfhi(w0.z), bflo(w0.w), bfhi(w0.w)};
        float wv2[8] = {bflo(w1.x), bfhi(w1.x), bflo(w1.y), bfhi(w1.y),
                        bflo(w1.z), bfhi(w1.z), bflo(w1.w), bfhi(w1.w)};
#pragma unroll
        for (int e = 0; e < 8; ++e) {
            a0 = fmaf(fa[e], wv[e], a0);
            a1 = fmaf(fb[e], wv[e], a1);
        }
#pragma unroll
        for (int e = 0; e < 8; ++e) {
            a0 = fmaf(fa[8 + e], wv2[e], a0);
            a1 = fmaf(fb[8 + e], wv2[e], a1);
        }
    }
#pragma unroll
    for (int o = 32; o; o >>= 1) {
        a0 += __shfl_down(a0, o);
        a1 += __shfl_down(a1, o);
    }
    o0 = a0; o1 = a1;
}

// fused builder: one dist read -> M1[c] and M2T[c]
__device__ __forceinline__ void build_dual(const float* __restrict__ dist,
                                           const float* __restrict__ rm1,
                                           const float* __restrict__ d12,
                                           unsigned char* __restrict__ M1,
                                           unsigned char* __restrict__ M2T, int c) {
    int i = c >> 10;
    int j = (c & 1023) << 3;
    float rm = rm1[i];
    const float* Dr = dist + (size_t)i * DC + OFF + j;
    float4 d0 = *(const float4*)Dr;
    float4 d1 = *(const float4*)(Dr + 4);
    float4 e0 = *(const float4*)(d12 + j);
    float4 e1 = *(const float4*)(d12 + j + 4);
    float dv[8] = {d0.x, d0.y, d0.z, d0.w, d1.x, d1.y, d1.z, d1.w};
    float dd[8] = {e0.x, e0.y, e0.z, e0.w, e1.x, e1.y, e1.z, e1.w};
    float v1[8], v2[8];
#pragma unroll
    for (int k = 0; k < 8; ++k) {
        int jj = j + k;
        bool dg1 = (jj == i) || (jj == i + 4096);
        float g1 = dg1 ? 0.0f : fmaxf(0.05f + dv[k] - rm, 0.0f);
        v1[k] = __expf(5.0f * __expf(-g1));
        bool dg2 = (i == (jj & 4095));
        float g2 = dg2 ? 0.0f : fmaxf(0.05f + dv[k] - dd[k], 0.0f);
        v2[k] = __expf(5.0f * __expf(-g2));
    }
    uint2 o1, o2;
    o1.x = pk4_fp8(v1[0], v1[1], v1[2], v1[3]);
    o1.y = pk4_fp8(v1[4], v1[5], v1[6], v1[7]);
    o2.x = pk4_fp8(v2[0], v2[1], v2[2], v2[3]);
    o2.y = pk4_fp8(v2[4], v2[5], v2[6], v2[7]);
    *(uint2*)(M1 + (size_t)c * 8) = o1;
    *(uint2*)(M2T + (size_t)c * 8) = o2;
}

// 64x64 byte tile transpose: S (4096x8192) -> D (8192x4096)
__device__ __forceinline__ void tile_transpose8(const unsigned char* __restrict__ S,
                                                unsigned char* __restrict__ D,
                                                unsigned int (*t32)[17], int t, int tid) {
    int r0 = (t >> 7) * 64;
    int c0 = (t & 127) * 64;
    int rr = tid >> 2, lc = tid & 3;
    uint4 a = *(const uint4*)(S + (size_t)(r0 + rr) * NC + c0 + lc * 16);
    t32[rr][lc * 4 + 0] = a.x;
    t32[rr][lc * 4 + 1] = a.y;
    t32[rr][lc * 4 + 2] = a.z;
    t32[rr][lc * 4 + 3] = a.w;
    __syncthreads();
    int cc = tid >> 2, seg = tid & 3;
    unsigned int o[4];
#pragma unroll
    for (int q4 = 0; q4 < 4; ++q4) {
        unsigned int v = 0;
#pragma unroll
        for (int b = 0; b < 4; ++b) {
            int srow = seg * 16 + q4 * 4 + b;
            unsigned int w = t32[srow][cc >> 2];
            v |= ((w >> ((cc & 3) * 8)) & 0xffu) << (b * 8);
        }
        o[q4] = v;
    }
    *(uint4*)(D + (size_t)(c0 + cc) * NR + r0 + seg * 16) = make_uint4(o[0], o[1], o[2], o[3]);
    __syncthreads();
}

// ------------------------- cooperative dual-loss kernel --------------------
__global__ __launch_bounds__(BLK, 4) void k_main(const float* __restrict__ dist,
                                                 float* __restrict__ out,
                                                 unsigned char* __restrict__ M1,
                                                 unsigned char* __restrict__ MT1,
                                                 unsigned char* __restrict__ M2T,
                                                 unsigned char* __restrict__ MT2,
                                                 unsigned short* __restrict__ w_c1,
                                                 unsigned short* __restrict__ w_c2,
                                                 unsigned short* __restrict__ w_r1,
                                                 unsigned short* __restrict__ w_r2,
                                                 float* __restrict__ rm1,
                                                 int* __restrict__ arg1,
                                                 float* __restrict__ d12,
                                                 float* __restrict__ numb,
                                                 float* __restrict__ denb,
                                                 unsigned int* __restrict__ ctrs,
                                                 unsigned int* __restrict__ rel) {
    cg::grid_group grid = cg::this_grid();
    const int tid = threadIdx.x, bid = blockIdx.x;
    const int nb = gridDim.x, nt = nb * BLK;
    const int gt = bid * BLK + tid;
    const int nw = nt >> 6, wave = gt >> 6, lane = tid & 63;
    const int cpl = nb >> 6;
    unsigned int pc = 0;

    extern __shared__ char smem[];                // 24832 B
    ull* lds64 = (ull*)smem;                      // 1536 uint4 slots (24 KB)
    const uint4* vv4 = (const uint4*)smem;
    unsigned int (*tile)[17] = (unsigned int(*)[17])smem;
    float* wsm = (float*)(smem + 24576);          // 32 floats

    // ---------------- init ----------------
    for (int t = gt; t < NC; t += nt) {
        if (t == 0) __hip_atomic_store(out, 0.0f, __ATOMIC_RELAXED, AGENT);
        if (t < NR) {
            float a = dist[(size_t)t * DC + OFF + t];
            float b = dist[(size_t)t * DC + OFF + 4096 + t];
            rm1[t] = fmaxf(a, b);
            arg1[t] = (a >= b) ? t : t + 4096;
            st_wbf(&w_r1[t], INV4096);            // u1_0
        }
        d12[t] = dist[(size_t)(t & 4095) * DC + OFF + t];
        st_wbf(&w_c2[t], INV8192);                // u2_0
        __hip_atomic_store(&numb[t], 0.0f, __ATOMIC_RELAXED, AGENT);
        __hip_atomic_store(&denb[t], 0.0f, __ATOMIC_RELAXED, AGENT);
    }
    grid.sync();
    for (int c = gt; c < NR * NC / 8; c += nt) build_dual(dist, rm1, d12, M1, M2T, c);
    grid.sync();
    for (int t = bid; t < 16384; t += nb) {
        if (t < 8192) tile_transpose8(M1, MT1, tile, t, tid);
        else          tile_transpose8(M2T, MT2, tile, t - 8192, tid);
    }
    grid.sync();

    // ---------------- interleaved Sinkhorn: 99 phases ----------------
    // ph even: [A1: w_c1 <- MT1 . w_r1 | B2: w_r2 <- M2T . w_c2]
    // ph odd : [B1: w_r1 <- M1 . w_c1 | A2: w_c2 <- MT2 . w_r2]
    for (int t = 0; t < 99; ++t) {
        bool ph1 = ((t & 1) == 0);
        const unsigned char* P = ph1 ? MT1 : MT2;   // 8192 x 4096
        const unsigned char* Q = ph1 ? M2T : M1;    // 4096 x 8192
        const unsigned short* wPs = ph1 ? w_r1 : w_r2;
        const unsigned short* wQs = ph1 ? w_c2 : w_c1;
        unsigned short* Pout = ph1 ? w_c1 : w_c2;
        unsigned short* Qout = ph1 ? w_r2 : w_r1;
        stage2(wQs, wPs, lds64, tid);
        for (int r = wave; r < NR; r += nw) {
            float s = dotQ(Q + (size_t)r * NC, vv4, lane);
            if (lane == 0) st_wbf(&Qout[r], __fdividef(INV4096, s));
        }
        for (int r = wave; r < NR; r += nw) {
            float s0, s1;
            dotP2(P + (size_t)r * 4096, P + (size_t)(r + 4096) * 4096,
                  vv4 + 1024, lane, s0, s1);
            if (lane == 0) {
                st_wbf(&Pout[r], __fdividef(INV8192, s0));
                st_wbf(&Pout[r + 4096], __fdividef(INV8192, s1));
            }
        }
        gbar(ctrs, rel, ++pc, bid, cpl);
    }

    // ---------------- epilogues (concurrent, K recomputed in f32) ----------
    stage2(w_c1, w_r2, lds64, tid);               // Q region <- v1 weights
    // epi2: 1024 stripes of 32 rows over the (implicit) M2T domain
    for (int t2 = bid; t2 < 1024; t2 += nb) {
        int r0 = (t2 >> 3) * 32;
        int c = (t2 & 7) * 1024 + tid * 4;
        if (tid < 32) wsm[tid] = ld_wbf(&w_r2[r0 + tid]);
        __syncthreads();
        float4 e0 = *(const float4*)(d12 + c);
        float dd[4] = {e0.x, e0.y, e0.z, e0.w};
        float nacc[4] = {0.f, 0.f, 0.f, 0.f};
        float dacc[4] = {0.f, 0.f, 0.f, 0.f};
        for (int r = 0; r < 32; ++r) {
            int rr = r0 + r;
            float4 dv4 = *(const float4*)(dist + (size_t)rr * DC + OFF + c);
            float dv[4] = {dv4.x, dv4.y, dv4.z, dv4.w};
            float ww = wsm[r];
#pragma unroll
            for (int e = 0; e < 4; ++e) {
                int cc = c + e;
                bool isdiag = (rr == (cc & 4095));
                float gm = fmaxf(0.05f + dv[e] - dd[e], 0.0f);
                float K = __expf(5.0f * __expf(-gm));
                float wv = isdiag ? 0.0f : K * ww;
                nacc[e] += wv * gm;
                dacc[e] += wv;
            }
        }
#pragma unroll
        for (int e = 0; e < 4; ++e) {
            atomicAdd(&numb[c + e], nacc[e]);
            atomicAdd(&denb[c + e], dacc[e]);
        }
        __syncthreads();
    }
    // epi1: per-row, weights from LDS (bitwise-identical to round 8)
    for (int i = wave; i < NR; i += nw) {
        float rm = rm1[i];
        int arg = arg1[i];
        const float* Dr = dist + (size_t)i * DC + OFF;
        float num = 0.0f, den = 0.0f;
#pragma unroll 2
        for (int k = 0; k < 8; ++k) {
#pragma unroll
            for (int h = 0; h < 2; ++h) {
                int j0 = k * 1024 + h * 512 + lane * 8;
                int slot = k * 128 + (lane & 1) * 64 + h * 32 + (lane >> 1);
                uint4 w = vv4[slot];
                float4 d0 = *(const float4*)(Dr + j0);
                float4 d1 = *(const float4*)(Dr + j0 + 4);
                float tv[8] = {bflo(w.x), bfhi(w.x), bflo(w.y), bfhi(w.y),
                               bflo(w.z), bfhi(w.z), bflo(w.w), bfhi(w.w)};
                float dv[8] = {d0.x, d0.y, d0.z, d0.w, d1.x, d1.y, d1.z, d1.w};
#pragma unroll
                for (int e = 0; e < 8; ++e) {
                    int jj = j0 + e;
                    bool isdiag = (jj == i) || (jj == i + 4096);
                    float goff = fmaxf(0.05f + dv[e] - rm, 0.0f);
                    float K = __expf(5.0f * __expf(-(isdiag ? 0.0f : goff)));
                    float gm = isdiag ? fmaxf(rm - 0.5f - dv[e], 0.0f) : goff;
                    bool keep = (jj != arg) && ((jj < 4096) || (jj == i + 4096));
                    float wv = keep ? K * tv[e] : 0.0f;
                    num += wv * gm;
                    den += wv;
                }
            }
        }
#pragma unroll
        for (int o = 32; o; o >>= 1) {
            num += __shfl_down(num, o);
            den += __shfl_down(den, o);
        }
        if (lane == 0) atomicAdd(out, num / den);
    }
    gbar(ctrs, rel, ++pc, bid, cpl);
    for (int t2 = wave; t2 < 128; t2 += nw) {
        int c = t2 * 64 + lane;
        float n = __hip_atomic_load(&numb[c], __ATOMIC_RELAXED, AGENT);
        float d = __hip_atomic_load(&denb[c], __ATOMIC_RELAXED, AGENT);
        float v = n / d;
#pragma unroll
        for (int o = 32; o; o >>= 1) v += __shfl_down(v, o);
        if (lane == 0) atomicAdd(out, v);
    }
}

// ------------------------- fallback multi-kernel path (bf16, proven) -------
__device__ __forceinline__ void fb_build1(const float* __restrict__ dist,
                                          const float* __restrict__ rm1,
                                          unsigned short* __restrict__ M, int c) {
    int i = c >> 10;
    int j = (c & 1023) << 3;
    float rm = rm1[i];
    const float* Dr = dist + (size_t)i * DC + OFF + j;
    float4 d0 = *(const float4*)Dr;
    float4 d1 = *(const float4*)(Dr + 4);
    float dv[8] = {d0.x, d0.y, d0.z, d0.w, d1.x, d1.y, d1.z, d1.w};
    unsigned short e[8];
#pragma unroll
    for (int k = 0; k < 8; ++k) {
        int jj = j + k;
        bool diag = (jj == i) || (jj == i + 4096);
        float gm = diag ? 0.0f : fmaxf(0.05f + dv[k] - rm, 0.0f);
        e[k] = f2bf(__expf(5.0f * __expf(-gm)));
    }
    uint4 o;
    o.x = (unsigned int)e[0] | ((unsigned int)e[1] << 16);
    o.y = (unsigned int)e[2] | ((unsigned int)e[3] << 16);
    o.z = (unsigned int)e[4] | ((unsigned int)e[5] << 16);
    o.w = (unsigned int)e[6] | ((unsigned int)e[7] << 16);
    *(uint4*)(M + (size_t)c * 8) = o;
}
__device__ __forceinline__ void fb_build2(const float* __restrict__ dist,
                                          const float* __restrict__ d12,
                                          unsigned short* __restrict__ M, int c) {
    int r = c >> 10;
    int col = (c & 1023) << 3;
    const float* Dr = dist + (size_t)r * DC + OFF + col;
    float4 d0 = *(const float4*)Dr;
    float4 d1 = *(const float4*)(Dr + 4);
    float4 e0 = *(const float4*)(d12 + col);
    float4 e1 = *(const float4*)(d12 + col + 4);
    float dv[8] = {d0.x, d0.y, d0.z, d0.w, d1.x, d1.y, d1.z, d1.w};
    float dd[8] = {e0.x, e0.y, e0.z, e0.w, e1.x, e1.y, e1.z, e1.w};
    unsigned short e[8];
#pragma unroll
    for (int k = 0; k < 8; ++k) {
        int cc = col + k;
        bool diag = (r == (cc & 4095));
        float gm = diag ? 0.0f : fmaxf(0.05f + dv[k] - dd[k], 0.0f);
        e[k] = f2bf(__expf(5.0f * __expf(-gm)));
    }
    uint4 o;
    o.x = (unsigned int)e[0] | ((unsigned int)e[1] << 16);
    o.y = (unsigned int)e[2] | ((unsigned int)e[3] << 16);
    o.z = (unsigned int)e[4] | ((unsigned int)e[5] << 16);
    o.w = (unsigned int)e[6] | ((unsigned int)e[7] << 16);
    *(uint4*)(M + (size_t)c * 8) = o;
}
__device__ __forceinline__ void fb_transpose(const unsigned short* __restrict__ M,
                                             unsigned short* __restrict__ MT,
                                             unsigned int (*tile)[33], int t, int tid) {
    int r0 = (t >> 7) * 64;
    int c0 = (t & 127) * 64;
    int lc = tid & 7, rr = tid >> 3;
#pragma unroll
    for (int s = 0; s < 2; ++s) {
        int r = rr + s * 32;
        uint4 a = *(const uint4*)(M + (size_t)(r0 + r) * NC + c0 + lc * 8);
        tile[r][lc * 4 + 0] = a.x;
        tile[r][lc * 4 + 1] = a.y;
        tile[r][lc * 4 + 2] = a.z;
        tile[r][lc * 4 + 3] = a.w;
    }
    __syncthreads();
    int cc = tid >> 2, rs = (tid & 3) * 16;
    unsigned int o[8];
#pragma unroll
    for (int w = 0; w < 8; ++w) {
        unsigned int ue = tile[rs + 2 * w][cc >> 1];
        unsigned int uo = tile[rs + 2 * w + 1][cc >> 1];
        unsigned short e = (cc & 1) ? (unsigned short)(ue >> 16) : (unsigned short)(ue & 0xffffu);
        unsigned short d = (cc & 1) ? (unsigned short)(uo >> 16) : (unsigned short)(uo & 0xffffu);
        o[w] = (unsigned int)e | ((unsigned int)d << 16);
    }
    unsigned short* dst = MT + (size_t)(c0 + cc) * NR + r0 + rs;
    *(uint4*)dst = make_uint4(o[0], o[1], o[2], o[3]);
    *(uint4*)(dst + 8) = make_uint4(o[4], o[5], o[6], o[7]);
    __syncthreads();
}
template <int W>
__device__ __forceinline__ float rowdot_g(const unsigned short* __restrict__ row,
                                          const float* __restrict__ w, int lane) {
    float acc = 0.0f;
#pragma unroll
    for (int s = 0; s < W; s += 512) {
        int j = s + lane * 8;
        uint4 a = *(const uint4*)(row + j);
        float4 w0 = *(const float4*)(w + j);
        float4 w1 = *(const float4*)(w + j + 4);
        acc = fmaf(bflo(a.x), w0.x, acc);
        acc = fmaf(bfhi(a.x), w0.y, acc);
        acc = fmaf(bflo(a.y), w0.z, acc);
        acc = fmaf(bfhi(a.y), w0.w, acc);
        acc = fmaf(bflo(a.z), w1.x, acc);
        acc = fmaf(bfhi(a.z), w1.y, acc);
        acc = fmaf(bflo(a.w), w1.z, acc);
        acc = fmaf(bfhi(a.w), w1.w, acc);
    }
#pragma unroll
    for (int o = 32; o; o >>= 1) acc += __shfl_down(acc, o);
    return acc;
}
__global__ __launch_bounds__(BLK) void k_fb_init(const float* __restrict__ dist,
                                                 float* __restrict__ rm1, int* __restrict__ arg1,
                                                 float* __restrict__ d12, float* __restrict__ wrow,
                                                 float* __restrict__ out) {
    int t = blockIdx.x * BLK + threadIdx.x;
    if (t == 0) out[0] = 0.0f;
    if (t < NR) {
        float a = dist[(size_t)t * DC + OFF + t];
        float b = dist[(size_t)t * DC + OFF + 4096 + t];
        rm1[t] = fmaxf(a, b);
        arg1[t] = (a >= b) ? t : t + 4096;
        wrow[t] = INV4096;
    }
    d12[t] = dist[(size_t)(t & 4095) * DC + OFF + t];
}
__global__ __launch_bounds__(BLK) void k_fb_build1(const float* __restrict__ dist,
                                                   const float* __restrict__ rm1,
                                                   unsigned short* __restrict__ M) {
    fb_build1(dist, rm1, M, blockIdx.x * BLK + threadIdx.x);
}
__global__ __launch_bounds__(BLK) void k_fb_build2(const float* __restrict__ dist,
                                                   const float* __restrict__ d12,
                                                   unsigned short* __restrict__ M) {
    fb_build2(dist, d12, M, blockIdx.x * BLK + threadIdx.x);
}
__global__ __launch_bounds__(BLK) void k_fb_transp(const unsigned short* __restrict__ M,
                                                   unsigned short* __restrict__ MT) {
    __shared__ unsigned int tile[64][33];
    fb_transpose(M, MT, tile, blockIdx.x, threadIdx.x);
}
template <int W>
__global__ __launch_bounds__(BLK) void k_fb_matvec(const unsigned short* __restrict__ Mat,
                                                   const float* __restrict__ w,
                                                   float* __restrict__ outv, float scale) {
    int r = blockIdx.x * 4 + (threadIdx.x >> 6);
    float s = rowdot_g<W>(Mat + (size_t)r * W, w, threadIdx.x & 63);
    if ((threadIdx.x & 63) == 0) outv[r] = __fdividef(scale, s);
}
__global__ __launch_bounds__(BLK) void k_fb_epi1(const unsigned short* __restrict__ M,
                                                 const float* __restrict__ dist,
                                                 const float* __restrict__ wcol,
                                                 const float* __restrict__ rm1,
                                                 const int* __restrict__ arg1,
                                                 float* __restrict__ out) {
    int i = blockIdx.x * 4 + (threadIdx.x >> 6);
    int lane = threadIdx.x & 63;
    float rm = rm1[i];
    int arg = arg1[i];
    const unsigned short* Ar = M + (size_t)i * NC;
    const float* Dr = dist + (size_t)i * DC + OFF;
    float num = 0.0f, den = 0.0f;
#pragma unroll 4
    for (int s = 0; s < NC; s += 512) {
        int j0 = s + lane * 8;
        uint4 a = *(const uint4*)(Ar + j0);
        float4 t0 = *(const float4*)(wcol + j0);
        float4 t1 = *(const float4*)(wcol + j0 + 4);
        float4 d0 = *(const float4*)(Dr + j0);
        float4 d1 = *(const float4*)(Dr + j0 + 4);
        float av[8] = {bflo(a.x), bfhi(a.x), bflo(a.y), bfhi(a.y),
                       bflo(a.z), bfhi(a.z), bflo(a.w), bfhi(a.w)};
        float tv[8] = {t0.x, t0.y, t0.z, t0.w, t1.x, t1.y, t1.z, t1.w};
        float dv[8] = {d0.x, d0.y, d0.z, d0.w, d1.x, d1.y, d1.z, d1.w};
#pragma unroll
        for (int e = 0; e < 8; ++e) {
            int jj = j0 + e;
            bool isdiag = (jj == i) || (jj == i + 4096);
            float gm = isdiag ? fmaxf(rm - 0.5f - dv[e], 0.0f)
                              : fmaxf(0.05f + dv[e] - rm, 0.0f);
            bool keep = (jj != arg) && ((jj < 4096) || (jj == i + 4096));
            float wv = keep ? av[e] * tv[e] : 0.0f;
            num += wv * gm;
            den += wv;
        }
    }
#pragma unroll
    for (int o = 32; o; o >>= 1) {
        num += __shfl_down(num, o);
        den += __shfl_down(den, o);
    }
    if (lane == 0) atomicAdd(out, num / den);
}
__global__ __launch_bounds__(BLK) void k_fb_init2(float* __restrict__ wcol,
                                                  float* __restrict__ numb,
                                                  float* __restrict__ denb) {
    int t = blockIdx.x * BLK + threadIdx.x;
    wcol[t] = INV8192;
    numb[t] = 0.0f;
    denb[t] = 0.0f;
}
__global__ __launch_bounds__(BLK) void k_fb_epi2(const unsigned short* __restrict__ M,
                                                 const float* __restrict__ dist,
                                                 const float* __restrict__ wrow,
                                                 const float* __restrict__ d12,
                                                 float* __restrict__ numb,
                                                 float* __restrict__ denb) {
    __shared__ float wsm[64];
    int t = blockIdx.x, tid = threadIdx.x;
    int r0 = (t >> 3) * 64;
    int c = (t & 7) * 1024 + tid * 4;
    if (tid < 64) wsm[tid] = wrow[r0 + tid];
    __syncthreads();
    float4 e0 = *(const float4*)(d12 + c);
    float dd[4] = {e0.x, e0.y, e0.z, e0.w};
    float nacc[4] = {0.f, 0.f, 0.f, 0.f};
    float dacc[4] = {0.f, 0.f, 0.f, 0.f};
    for (int r = 0; r < 64; ++r) {
        int rr = r0 + r;
        uint2 a = *(const uint2*)(M + (size_t)rr * NC + c);
        float4 dv4 = *(const float4*)(dist + (size_t)rr * DC + OFF + c);
        float av[4] = {bflo(a.x), bfhi(a.x), bflo(a.y), bfhi(a.y)};
        float dv[4] = {dv4.x, dv4.y, dv4.z, dv4.w};
        float ww = wsm[r];
#pragma unroll
        for (int e = 0; e < 4; ++e) {
            int cc = c + e;
            bool isdiag = (rr == (cc & 4095));
            float gm = fmaxf(0.05f + dv[e] - dd[e], 0.0f);
            float wv = isdiag ? 0.0f : av[e] * ww;
            nacc[e] += wv * gm;
            dacc[e] += wv;
        }
    }
#pragma unroll
    for (int e = 0; e < 4; ++e) {
        atomicAdd(&numb[c + e], nacc[e]);
        atomicAdd(&denb[c + e], dacc[e]);
    }
}
__global__ __launch_bounds__(BLK) void k_fb_epi2fin(const float* __restrict__ numb,
                                                    const float* __restrict__ denb,
                                                    float* __restrict__ out) {
    int c = blockIdx.x * BLK + threadIdx.x;
    float v = numb[c] / denb[c];
    __shared__ float sm[4];
#pragma unroll
    for (int o = 32; o; o >>= 1) v += __shfl_down(v, o);
    if ((threadIdx.x & 63) == 0) sm[threadIdx.x >> 6] = v;
    __syncthreads();
    if (threadIdx.x == 0) atomicAdd(out, sm[0] + sm[1] + sm[2] + sm[3]);
}

// ---------------------------------------------------------------------------
extern "C" void kernel_launch(void* const* d_in, const int* in_sizes, int n_in,
                              void* d_out, int out_size, void* d_ws, size_t ws_size,
                              hipStream_t stream) {
    const float* dist = (const float*)d_in[0];
    float* out = (float*)d_out;

    const size_t MB32 = (size_t)NR * NC;          // 33.55 MB per fp8 matrix
    unsigned char* M1  = (unsigned char*)d_ws;
    unsigned char* MT1 = M1 + MB32;
    unsigned char* M2T = MT1 + MB32;
    unsigned char* MT2 = M2T + MB32;
    // fallback overlays the same 128 MiB with two bf16 matrices
    unsigned short* Mfb  = (unsigned short*)d_ws;
    unsigned short* MTfb = Mfb + MB32;
    // aux beyond 128 MiB
    unsigned short* w_c1 = (unsigned short*)((char*)d_ws + 4 * MB32);
    unsigned short* w_c2 = w_c1 + NC;
    unsigned short* w_r1 = w_c2 + NC;
    unsigned short* w_r2 = w_r1 + NR;
    float* fbf   = (float*)(w_r2 + NR);
    float* wrowF = fbf;
    float* wcolF = wrowF + NR;
    float* rm1  = wcolF + NC;
    int*   arg1 = (int*)(rm1 + NR);
    float* d12  = (float*)(arg1 + NR);
    float* numb = d12 + NC;
    float* denb = numb + NC;
    unsigned int* ctrs = (unsigned int*)(denb + NC);
    unsigned int* rel  = ctrs + 64 * 16;

    const unsigned int SMEM = 24832;

    int dev = 0;
    (void)hipGetDevice(&dev);
    int numCU = 0;
    (void)hipDeviceGetAttribute(&numCU, hipDeviceAttributeMultiprocessorCount, dev);
    int maxPerCU = 0;
    (void)hipOccupancyMaxActiveBlocksPerMultiprocessor(&maxPerCU, (const void*)k_main,
                                                       BLK, SMEM);
    hipError_t rc = hipErrorUnknown;
    int cand = (numCU > 0 && maxPerCU > 0) ? maxPerCU * numCU : 0;
    if (cand > 1024) cand = 1024;
    int grid = 0;
    if (cand >= 128) { grid = 128; while (grid * 2 <= cand) grid *= 2; }
    if (grid > 0) {
        (void)hipMemsetAsync(ctrs, 0, 2 * 64 * 16 * sizeof(unsigned int), stream);
        void* args[] = {(void*)&dist, (void*)&out, (void*)&M1, (void*)&MT1,
                        (void*)&M2T, (void*)&MT2,
                        (void*)&w_c1, (void*)&w_c2, (void*)&w_r1, (void*)&w_r2,
                        (void*)&rm1, (void*)&arg1, (void*)&d12,
                        (void*)&numb, (void*)&denb, (void*)&ctrs, (void*)&rel};
        for (int g = grid; g >= 128 && rc != hipSuccess; g >>= 1) {
            rc = hipLaunchCooperativeKernel((void*)k_main, dim3(g), dim3(BLK),
                                            args, SMEM, stream);
            if (rc != hipSuccess) (void)hipGetLastError();
        }
    }
    if (rc == hipSuccess) return;

    // ---- fallback: multi-kernel graph path (guaranteed) ----
    k_fb_init<<<32, BLK, 0, stream>>>(dist, rm1, arg1, d12, wrowF, out);
    k_fb_build1<<<16384, BLK, 0, stream>>>(dist, rm1, Mfb);
    k_fb_transp<<<8192, BLK, 0, stream>>>(Mfb, MTfb);
    for (int it = 0; it < 50; ++it) {
        k_fb_matvec<NR><<<2048, BLK, 0, stream>>>(MTfb, wrowF, wcolF, INV8192);
        if (it == 49) break;
        k_fb_matvec<NC><<<1024, BLK, 0, stream>>>(Mfb, wcolF, wrowF, INV4096);
    }
    k_fb_epi1<<<1024, BLK, 0, stream>>>(Mfb, dist, wcolF, rm1, arg1, out);

    k_fb_build2<<<16384, BLK, 0, stream>>>(dist, d12, Mfb);
    k_fb_init2<<<32, BLK, 0, stream>>>(wcolF, numb, denb);
    k_fb_transp<<<8192, BLK, 0, stream>>>(Mfb, MTfb);
    for (int it = 0; it < 50; ++it) {
        k_fb_matvec<NC><<<1024, BLK, 0, stream>>>(Mfb, wcolF, wrowF, INV4096);
        if (it == 49) break;
        k_fb_matvec<NR><<<2048, BLK, 0, stream>>>(MTfb, wrowF, wcolF, INV8192);
    }
    k_fb_epi2<<<512, BLK, 0, stream>>>(Mfb, dist, wrowF, d12, numb, denb);
    k_fb_epi2fin<<<32, BLK, 0, stream>>>(numb, denb, out);
}